// Round 2
// baseline (1054.719 us; speedup 1.0000x reference)
//
#include <hip/hip_runtime.h>
#include <hip/hip_bf16.h>

typedef unsigned int u32;
typedef unsigned short u16;

#define DIMN 256
#define TLEN 256

// ---------------------------------------------------------------------------
// helpers
// ---------------------------------------------------------------------------
typedef _Float16 half2v __attribute__((ext_vector_type(2)));
typedef _Float16 f16x8  __attribute__((ext_vector_type(8)));
typedef float    f32x4  __attribute__((ext_vector_type(4)));

__device__ __forceinline__ u32 packh2(float lo, float hi) {
    _Float16 l = (_Float16)lo, h = (_Float16)hi;
    u16 lu = __builtin_bit_cast(u16, l);
    u16 hu = __builtin_bit_cast(u16, h);
    return (u32)lu | ((u32)hu << 16);
}

__device__ __forceinline__ float h2lo(u32 v) {
    return (float)__builtin_bit_cast(half2v, v).x;
}
__device__ __forceinline__ float h2hi(u32 v) {
    return (float)__builtin_bit_cast(half2v, v).y;
}

// LDS-only barrier: make our ds_writes visible, sync, and fence so the
// following ds_reads cannot hoist above the barrier. Crucially does NOT
// drain vmcnt - outstanding global loads (Z prefetch) and stores (H)
// stay in flight across the barrier.
__device__ __forceinline__ void lds_barrier() {
    asm volatile("s_waitcnt lgkmcnt(0)" ::: "memory");
    __builtin_amdgcn_s_barrier();
    asm volatile("" ::: "memory");
}

// ---------------------------------------------------------------------------
// prep kernels: build P^T, S^T, W^T (fp32), then pack S/P as MFMA A-fragments
//   Pt[j*256+i] = P[i][j],  P = D^T F D
//   St[j*256+i] = S[i][j],  S = I - (1/a) D^T (A^T A + lam2 I) D
//   Wt[d*256+i] = W[i][d],  W = (1/a) D^T A^T A
// ---------------------------------------------------------------------------
__global__ void prep1(const float* __restrict__ A, const float* __restrict__ D,
                      const float* __restrict__ F, const float* __restrict__ lam2p,
                      float* __restrict__ FD, float* __restrict__ G,
                      float* __restrict__ AD) {
    int gid = blockIdx.x * 256 + threadIdx.x;
    if (gid < 65536) {                   // FD[k][j] = sum_q F[k][q] D[q][j]
        int k = gid >> 8, j = gid & 255;
        float s = 0.f;
        #pragma unroll 8
        for (int q = 0; q < 256; ++q) s += F[k*256+q] * D[q*256+j];
        FD[gid] = s;
    } else if (gid < 131072) {           // G[p][q] = sum_m A[m][p] A[m][q] + lam2*(p==q)
        int g = gid - 65536; int p = g >> 8, q = g & 255;
        float s = (p == q) ? lam2p[0] : 0.f;
        #pragma unroll 8
        for (int m = 0; m < 64; ++m) s += A[m*256+p] * A[m*256+q];
        G[g] = s;
    } else if (gid < 147456) {           // AD[m][i] = sum_k A[m][k] D[k][i]
        int g = gid - 131072; int m = g >> 8, i = g & 255;
        float s = 0.f;
        #pragma unroll 8
        for (int k = 0; k < 256; ++k) s += A[m*256+k] * D[k*256+i];
        AD[g] = s;
    }
}

__global__ void prep2(const float* __restrict__ A, const float* __restrict__ D,
                      const float* __restrict__ alphap,
                      const float* __restrict__ FD, const float* __restrict__ G,
                      const float* __restrict__ AD,
                      float* __restrict__ Pt, float* __restrict__ GD,
                      float* __restrict__ Wt) {
    int gid = blockIdx.x * 256 + threadIdx.x;
    float inva = 1.0f / alphap[0];
    if (gid < 65536) {                   // Pt[j][i] = sum_k D[k][i] FD[k][j]
        int j = gid >> 8, i = gid & 255;
        float s = 0.f;
        #pragma unroll 8
        for (int k = 0; k < 256; ++k) s += D[k*256+i] * FD[k*256+j];
        Pt[gid] = s;
    } else if (gid < 131072) {           // GD[k][j] = sum_q G[k][q] D[q][j]
        int g = gid - 65536; int k = g >> 8, j = g & 255;
        float s = 0.f;
        #pragma unroll 8
        for (int q = 0; q < 256; ++q) s += G[k*256+q] * D[q*256+j];
        GD[g] = s;
    } else {                             // Wt[d][i] = inva * sum_m AD[m][i] A[m][d]
        int g = gid - 131072; int d = g >> 8, i = g & 255;
        float s = 0.f;
        #pragma unroll 8
        for (int m = 0; m < 64; ++m) s += AD[m*256+i] * A[m*256+d];
        Wt[g] = inva * s;
    }
}

__global__ void prep3(const float* __restrict__ D, const float* __restrict__ GD,
                      const float* __restrict__ alphap, float* __restrict__ St) {
    int gid = blockIdx.x * 256 + threadIdx.x;   // 65536 threads
    int j = gid >> 8, i = gid & 255;
    float inva = 1.0f / alphap[0];
    float s = 0.f;
    #pragma unroll 8
    for (int k = 0; k < 256; ++k) s += D[k*256+i] * GD[k*256+j];
    St[gid] = ((i == j) ? 1.0f : 0.0f) - inva * s;
}

// Pack S and P as fp16 MFMA A-fragments for v_mfma_f32_16x16x32_f16.
// Fragment (tile tau in 0..15, kk in 0..7, lane l):
//   8 fp16 = M[row][k0..k0+8) with row = 16*tau + (l&15), k0 = 32*kk + 8*(l>>4)
// stored as uint4 at Sfrag[((tau*8+kk)*64 + l)*4].
__global__ void prep4(const float* __restrict__ St, const float* __restrict__ Pt,
                      u32* __restrict__ Sfrag, u32* __restrict__ Pfrag) {
    int gid = blockIdx.x * 256 + threadIdx.x;   // 16384 threads
    int idx = gid & 8191;
    int l   = idx & 63;
    int kk  = (idx >> 6) & 7;
    int tau = idx >> 9;
    int row = 16*tau + (l & 15);
    int k0  = 32*kk + 8*(l >> 4);
    const float* M = (gid < 8192) ? St : Pt;     // M[i][k] = Mt[k*256+i]
    u32* O = (gid < 8192) ? Sfrag : Pfrag;
    uint4 v;
    v.x = packh2(M[(k0+0)*256 + row], M[(k0+1)*256 + row]);
    v.y = packh2(M[(k0+2)*256 + row], M[(k0+3)*256 + row]);
    v.z = packh2(M[(k0+4)*256 + row], M[(k0+5)*256 + row]);
    v.w = packh2(M[(k0+6)*256 + row], M[(k0+7)*256 + row]);
    *(uint4*)&O[idx*4] = v;
}

// ---------------------------------------------------------------------------
// Z-GEMM: Z[b][t][i] = sum_d Wt[d*256+i] * y[b][d][t], written PACKED fp16:
//   Zh[(b*256+t)*128 + i/2] = (Z[b][t][i_even], Z[b][t][i_even+1])
// ---------------------------------------------------------------------------
__launch_bounds__(256, 2)
__global__ void zgemm(const float* __restrict__ y, const float* __restrict__ Wt,
                      u32* __restrict__ Zh) {
    __shared__ float ys[64][132];    // [dd][tt]
    __shared__ float wsh[64][132];   // [dd][ii]
    const int b  = blockIdx.x;
    const int t0 = (blockIdx.y & 1) * 128;
    const int i0 = (blockIdx.y >> 1) * 128;
    const int tid = threadIdx.x;
    const int tx = tid & 15;   // i-octet
    const int ty = tid >> 4;   // t-octet
    float acc[8][8];           // [c=t][a=i]
    #pragma unroll
    for (int c = 0; c < 8; ++c)
        #pragma unroll
        for (int a = 0; a < 8; ++a) acc[c][a] = 0.f;

    for (int dc = 0; dc < 256; dc += 64) {
        #pragma unroll
        for (int k = 0; k < 8; ++k) {
            int idx = k * 256 + tid;
            int row = idx >> 5, col4 = idx & 31;
            float4 yv = *(const float4*)&y[((size_t)b*256 + dc + row)*256 + t0 + col4*4];
            float4 wv = *(const float4*)&Wt[(size_t)(dc + row)*256 + i0 + col4*4];
            *(float4*)&ys[row][col4*4]  = yv;
            *(float4*)&wsh[row][col4*4] = wv;
        }
        __syncthreads();
        #pragma unroll 4
        for (int dd = 0; dd < 64; ++dd) {
            float4 w0 = *(const float4*)&wsh[dd][8*tx];
            float4 w1 = *(const float4*)&wsh[dd][8*tx+4];
            float4 y0 = *(const float4*)&ys[dd][8*ty];
            float4 y1 = *(const float4*)&ys[dd][8*ty+4];
            float wv[8] = {w0.x,w0.y,w0.z,w0.w,w1.x,w1.y,w1.z,w1.w};
            float yv[8] = {y0.x,y0.y,y0.z,y0.w,y1.x,y1.y,y1.z,y1.w};
            #pragma unroll
            for (int c = 0; c < 8; ++c)
                #pragma unroll
                for (int a = 0; a < 8; ++a) acc[c][a] += wv[a] * yv[c];
        }
        __syncthreads();
    }
    #pragma unroll
    for (int c = 0; c < 8; ++c) {
        int t = t0 + 8*ty + c;
        uint4 pk;
        pk.x = packh2(acc[c][0], acc[c][1]);
        pk.y = packh2(acc[c][2], acc[c][3]);
        pk.z = packh2(acc[c][4], acc[c][5]);
        pk.w = packh2(acc[c][6], acc[c][7]);
        *(uint4*)&Zh[((size_t)b*256 + t)*128 + (i0 >> 1) + 4*tx] = pk;
    }
}

// ---------------------------------------------------------------------------
// scan7: MFMA scan, latency-trimmed. 16 blocks x 512 threads; block = 16
// batches, wave w owns rows 32w..32w+31 (tiles 2w, 2w+1). Per round:
// 8 ds_read_b128 of h B-frags + 16 MFMA in 4 independent depth-4 chains
// (S/P frags in AGPRs). Barriers are LDS-only (lgkmcnt) - Z prefetch and
// H stores stay in flight across them. 5 rounds/step.
// ---------------------------------------------------------------------------
__global__ __attribute__((amdgpu_flat_work_group_size(512, 512),
                          amdgpu_waves_per_eu(2, 2)))
void scan7(const u32* __restrict__ Sfrag, const u32* __restrict__ Pfrag,
           const u32* __restrict__ Zh,
           const float* __restrict__ h0, const float* __restrict__ U,
           const float* __restrict__ lam1p, const float* __restrict__ lam2p,
           const float* __restrict__ alphap,
           float* __restrict__ H) {
    __shared__ __align__(16) u32 hx[2 * 2048];   // 2 x 8 KB h B-fragment buffers

    const int tid = threadIdx.x;
    const int l   = tid & 63;
    const int w   = tid >> 6;          // wave 0..7
    const int lb  = l & 15;            // batch-in-group == MFMA col
    const int g   = l >> 4;            // 0..3
    const int b   = blockIdx.x * 16 + lb;

    const float inva = 1.0f / alphap[0];
    const float bt   = lam1p[0] * inva;
    const float c2   = lam2p[0] * inva;

    // per-lane rows: 32w + 16T + 4g + r
    const int rb = 32*w + 4*g;
    const float u00 = U[rb+0]*bt,  u01 = U[rb+1]*bt,  u02 = U[rb+2]*bt,  u03 = U[rb+3]*bt;
    const float u10 = U[rb+16]*bt, u11 = U[rb+17]*bt, u12 = U[rb+18]*bt, u13 = U[rb+19]*bt;

    // A-fragments -> (A)GPRs (coalesced uint4 loads)
    f16x8 Sf0[8], Sf1[8], Pf0[8], Pf1[8];
    #pragma unroll
    for (int kk = 0; kk < 8; ++kk) {
        Sf0[kk] = __builtin_bit_cast(f16x8, *(const uint4*)&Sfrag[(((2*w+0)*8 + kk)*64 + l)*4]);
        Sf1[kk] = __builtin_bit_cast(f16x8, *(const uint4*)&Sfrag[(((2*w+1)*8 + kk)*64 + l)*4]);
        Pf0[kk] = __builtin_bit_cast(f16x8, *(const uint4*)&Pfrag[(((2*w+0)*8 + kk)*64 + l)*4]);
        Pf1[kk] = __builtin_bit_cast(f16x8, *(const uint4*)&Pfrag[(((2*w+1)*8 + kk)*64 + l)*4]);
    }

    // init h_prev B-fragments (h0 is batch-independent: value depends on k only)
    {
        int k0 = 32*(tid >> 6) + 8*((tid & 63) >> 4);
        uint4 hv;
        hv.x = packh2(h0[k0+0], h0[k0+1]);
        hv.y = packh2(h0[k0+2], h0[k0+3]);
        hv.z = packh2(h0[k0+4], h0[k0+5]);
        hv.w = packh2(h0[k0+6], h0[k0+7]);
        *(uint4*)&hx[tid*4] = hv;
    }
    __syncthreads();

    // Z: uint2 at Zb[t*128 + 8T] covers i = 32w + 16T + 4g + {0..3}
    const u32* Zb = Zh + (size_t)b*32768 + 16*w + 2*g;
    float* Hb = H + (size_t)b*TLEN*DIMN + 32*w + 4*g;

    // write slot (u32 index inside a buffer) for this lane's tile-T=0 pair;
    // tile-T=1 is +128.  (kk = w slice; lane'' = (2T + (g>>1))*16 + lb)
    const int wb0 = w*256 + (((g>>1))*16 + lb)*4 + (g&1)*2;

    int ro = 0, wo = 2048;

    uint2 z0 = *(const uint2*)&Zb[0];
    uint2 z1 = *(const uint2*)&Zb[8];

    #pragma unroll 1
    for (int t = 0; t < TLEN; ++t) {
        const int tn = (t < TLEN-1) ? t + 1 : t;
        uint2 zn0 = *(const uint2*)&Zb[(size_t)tn*128];
        uint2 zn1 = *(const uint2*)&Zb[(size_t)tn*128 + 8];

        // ---- P-phase: ph = P @ h_prev ----
        f16x8 hb[8];
        #pragma unroll
        for (int kk = 0; kk < 8; ++kk)
            hb[kk] = __builtin_bit_cast(f16x8, *(const uint4*)&hx[ro + (kk*64 + l)*4]);
        f32x4 a0a = {0.f,0.f,0.f,0.f}, a0b = {0.f,0.f,0.f,0.f};
        f32x4 a1a = {0.f,0.f,0.f,0.f}, a1b = {0.f,0.f,0.f,0.f};
        #pragma unroll
        for (int kk = 0; kk < 4; ++kk) {
            a0a = __builtin_amdgcn_mfma_f32_16x16x32_f16(Pf0[kk],   hb[kk],   a0a, 0, 0, 0);
            a1a = __builtin_amdgcn_mfma_f32_16x16x32_f16(Pf1[kk],   hb[kk],   a1a, 0, 0, 0);
            a0b = __builtin_amdgcn_mfma_f32_16x16x32_f16(Pf0[kk+4], hb[kk+4], a0b, 0, 0, 0);
            a1b = __builtin_amdgcn_mfma_f32_16x16x32_f16(Pf1[kk+4], hb[kk+4], a1b, 0, 0, 0);
        }
        const f32x4 a0 = a0a + a0b;
        const f32x4 a1 = a1a + a1b;
        // h_iter0 = Ph (unthresholded)
        *(uint2*)&hx[wo + wb0]       = make_uint2(packh2(a0[0],a0[1]), packh2(a0[2],a0[3]));
        *(uint2*)&hx[wo + wb0 + 128] = make_uint2(packh2(a1[0],a1[1]), packh2(a1[2],a1[3]));
        lds_barrier();
        // const vector for this lane's own rows (overlaps iter-0 ds_reads)
        const float c00 = h2lo(z0.x) + c2*a0[0];
        const float c01 = h2hi(z0.x) + c2*a0[1];
        const float c02 = h2lo(z0.y) + c2*a0[2];
        const float c03 = h2hi(z0.y) + c2*a0[3];
        const float c10 = h2lo(z1.x) + c2*a1[0];
        const float c11 = h2hi(z1.x) + c2*a1[1];
        const float c12 = h2lo(z1.y) + c2*a1[2];
        const float c13 = h2hi(z1.y) + c2*a1[3];
        int rr = wo, ww = ro;

        // ---- 4 S-iterations: h = soft(S@h + const) ----
        #pragma unroll
        for (int it = 0; it < 4; ++it) {
            #pragma unroll
            for (int kk = 0; kk < 8; ++kk)
                hb[kk] = __builtin_bit_cast(f16x8, *(const uint4*)&hx[rr + (kk*64 + l)*4]);
            f32x4 s0a = {c00,c01,c02,c03};
            f32x4 s0b = {0.f,0.f,0.f,0.f};
            f32x4 s1a = {c10,c11,c12,c13};
            f32x4 s1b = {0.f,0.f,0.f,0.f};
            #pragma unroll
            for (int kk = 0; kk < 4; ++kk) {
                s0a = __builtin_amdgcn_mfma_f32_16x16x32_f16(Sf0[kk],   hb[kk],   s0a, 0, 0, 0);
                s1a = __builtin_amdgcn_mfma_f32_16x16x32_f16(Sf1[kk],   hb[kk],   s1a, 0, 0, 0);
                s0b = __builtin_amdgcn_mfma_f32_16x16x32_f16(Sf0[kk+4], hb[kk+4], s0b, 0, 0, 0);
                s1b = __builtin_amdgcn_mfma_f32_16x16x32_f16(Sf1[kk+4], hb[kk+4], s1b, 0, 0, 0);
            }
            const f32x4 s0 = s0a + s0b;
            const f32x4 s1 = s1a + s1b;
            float v, av;
            v = s0[0]; av = fabsf(v) - u00; const float h00 = (av > 0.f) ? copysignf(av, v) : 0.f;
            v = s0[1]; av = fabsf(v) - u01; const float h01 = (av > 0.f) ? copysignf(av, v) : 0.f;
            v = s0[2]; av = fabsf(v) - u02; const float h02 = (av > 0.f) ? copysignf(av, v) : 0.f;
            v = s0[3]; av = fabsf(v) - u03; const float h03 = (av > 0.f) ? copysignf(av, v) : 0.f;
            v = s1[0]; av = fabsf(v) - u10; const float h10 = (av > 0.f) ? copysignf(av, v) : 0.f;
            v = s1[1]; av = fabsf(v) - u11; const float h11 = (av > 0.f) ? copysignf(av, v) : 0.f;
            v = s1[2]; av = fabsf(v) - u12; const float h12 = (av > 0.f) ? copysignf(av, v) : 0.f;
            v = s1[3]; av = fabsf(v) - u13; const float h13 = (av > 0.f) ? copysignf(av, v) : 0.f;
            *(uint2*)&hx[ww + wb0]       = make_uint2(packh2(h00,h01), packh2(h02,h03));
            *(uint2*)&hx[ww + wb0 + 128] = make_uint2(packh2(h10,h11), packh2(h12,h13));
            lds_barrier();
            if (it == 3) {   // fire-and-forget after the barrier, off critical path
                *(float4*)&Hb[(size_t)t*DIMN]      = make_float4(h00, h01, h02, h03);
                *(float4*)&Hb[(size_t)t*DIMN + 16] = make_float4(h10, h11, h12, h13);
            }
            int tmp = rr; rr = ww; ww = tmp;
        }
        ro = rr; wo = ww;     // rr holds final h_t -> next step's h_prev
        z0 = zn0; z1 = zn1;
    }
}

// ---------------------------------------------------------------------------
// out-GEMM: out[b][n][t] = sum_d D[n][d] * H[b][t][d]
// ---------------------------------------------------------------------------
__launch_bounds__(256, 2)
__global__ void ogemm(const float* __restrict__ D, const float* __restrict__ H,
                      float* __restrict__ out) {
    __shared__ float Ds[64][132];   // [dd][nn]
    __shared__ float Hs[64][132];   // [dd][tt]
    const int b  = blockIdx.x;
    const int n0 = (blockIdx.y & 1) * 128;
    const int t0 = (blockIdx.y >> 1) * 128;
    const int tid = threadIdx.x;
    const int tx = tid & 15;   // n-octet
    const int ty = tid >> 4;   // t-octet
    float acc[8][8];           // [a=n][c=t]
    #pragma unroll
    for (int a = 0; a < 8; ++a)
        #pragma unroll
        for (int c = 0; c < 8; ++c) acc[a][c] = 0.f;

    for (int dc = 0; dc < 256; dc += 64) {
        #pragma unroll
        for (int k = 0; k < 8; ++k) {
            int idx = k * 256 + tid;
            int row = idx >> 4;                // nn or tt (128 rows)
            int d4  = idx & 15;                // 16 float4 across d-chunk
            float4 dv = *(const float4*)&D[((size_t)(n0 + row))*256 + dc + d4*4];
            float4 hv = *(const float4*)&H[((size_t)b*256 + t0 + row)*256 + dc + d4*4];
            Ds[d4*4+0][row] = dv.x; Ds[d4*4+1][row] = dv.y;
            Ds[d4*4+2][row] = dv.z; Ds[d4*4+3][row] = dv.w;
            Hs[d4*4+0][row] = hv.x; Hs[d4*4+1][row] = hv.y;
            Hs[d4*4+2][row] = hv.z; Hs[d4*4+3][row] = hv.w;
        }
        __syncthreads();
        #pragma unroll 4
        for (int dd = 0; dd < 64; ++dd) {
            float4 d0 = *(const float4*)&Ds[dd][8*tx];
            float4 d1 = *(const float4*)&Ds[dd][8*tx+4];
            float4 h0v = *(const float4*)&Hs[dd][8*ty];
            float4 h1v = *(const float4*)&Hs[dd][8*ty+4];
            float dv[8] = {d0.x,d0.y,d0.z,d0.w,d1.x,d1.y,d1.z,d1.w};
            float hv[8] = {h0v.x,h0v.y,h0v.z,h0v.w,h1v.x,h1v.y,h1v.z,h1v.w};
            #pragma unroll
            for (int a = 0; a < 8; ++a)
                #pragma unroll
                for (int c = 0; c < 8; ++c) acc[a][c] += dv[a] * hv[c];
        }
        __syncthreads();
    }
    #pragma unroll
    for (int a = 0; a < 8; ++a) {
        float* op = &out[((size_t)b*256 + n0 + 8*tx + a)*256 + t0 + 8*ty];
        *(float4*)(op)     = make_float4(acc[a][0], acc[a][1], acc[a][2], acc[a][3]);
        *(float4*)(op + 4) = make_float4(acc[a][4], acc[a][5], acc[a][6], acc[a][7]);
    }
}

// ---------------------------------------------------------------------------
extern "C" void kernel_launch(void* const* d_in, const int* in_sizes, int n_in,
                              void* d_out, int out_size, void* d_ws, size_t ws_size,
                              hipStream_t stream) {
    const float* y     = (const float*)d_in[0];
    const float* A     = (const float*)d_in[1];
    const float* D     = (const float*)d_in[2];
    const float* F     = (const float*)d_in[3];
    const float* lam1  = (const float*)d_in[4];
    const float* lam2  = (const float*)d_in[5];
    const float* alpha = (const float*)d_in[6];
    const float* h0    = (const float*)d_in[7];
    const float* U     = (const float*)d_in[8];
    float* out = (float*)d_out;
    float* ws  = (float*)d_ws;

    // ws layout (fp32-element offsets)
    const size_t oZ  = 0;           // Zh: 8.39M u32 packed fp16 (region 16.7M)
    const size_t oH  = 16777216;    // H fp32: 16.7M
    const size_t oWt = 33554432;
    const size_t oSt = 33619968;
    const size_t oPt = 33685504;
    const size_t oFD = 33751040;
    const size_t oG  = 33816576;
    const size_t oGD = 33882112;
    const size_t oAD = 33947648;
    const size_t oSh = 33964032;   // Sfrag u32 (32768)
    const size_t oPh = 33996800;   // Pfrag u32 (32768)

    u32*   Zh = (u32*)(ws + oZ);
    float* H  = ws + oH;
    float* Wt = ws + oWt; float* St = ws + oSt; float* Pt = ws + oPt;
    float* FD = ws + oFD; float* G  = ws + oG;  float* GD = ws + oGD;
    float* AD = ws + oAD;
    u32* Sfrag = (u32*)(ws + oSh);
    u32* Pfrag = (u32*)(ws + oPh);

    prep1<<<576, 256, 0, stream>>>(A, D, F, lam2, FD, G, AD);
    prep2<<<768, 256, 0, stream>>>(A, D, alpha, FD, G, AD, Pt, GD, Wt);
    prep3<<<256, 256, 0, stream>>>(D, GD, alpha, St);
    prep4<<<64, 256, 0, stream>>>(St, Pt, Sfrag, Pfrag);
    {
        dim3 g(256, 4);
        zgemm<<<g, 256, 0, stream>>>(y, Wt, Zh);
    }
    scan7<<<16, 512, 0, stream>>>(Sfrag, Pfrag, Zh, h0, U, lam1, lam2, alpha, H);
    {
        dim3 g(256, 4);
        ogemm<<<g, 256, 0, stream>>>(D, H, out);
    }
}

// Round 3
// 992.094 us; speedup vs baseline: 1.0631x; 1.0631x over previous
//
#include <hip/hip_runtime.h>
#include <hip/hip_bf16.h>

typedef unsigned int u32;
typedef unsigned short u16;

#define DIMN 256
#define TLEN 256

// ---------------------------------------------------------------------------
// helpers
// ---------------------------------------------------------------------------
typedef _Float16 half2v __attribute__((ext_vector_type(2)));
typedef _Float16 f16x8  __attribute__((ext_vector_type(8)));
typedef float    f32x4  __attribute__((ext_vector_type(4)));

__device__ __forceinline__ u32 packh2(float lo, float hi) {
    _Float16 l = (_Float16)lo, h = (_Float16)hi;
    u16 lu = __builtin_bit_cast(u16, l);
    u16 hu = __builtin_bit_cast(u16, h);
    return (u32)lu | ((u32)hu << 16);
}

__device__ __forceinline__ float h2lo(u32 v) {
    return (float)__builtin_bit_cast(half2v, v).x;
}
__device__ __forceinline__ float h2hi(u32 v) {
    return (float)__builtin_bit_cast(half2v, v).y;
}

// ---------------------------------------------------------------------------
// prep kernels: build P^T, S^T, W^T (fp32), then pack S/P as MFMA A-fragments
//   Pt[j*256+i] = P[i][j],  P = D^T F D
//   St[j*256+i] = S[i][j],  S = I - (1/a) D^T (A^T A + lam2 I) D
//   Wt[d*256+i] = W[i][d],  W = (1/a) D^T A^T A
// ---------------------------------------------------------------------------
__global__ void prep1(const float* __restrict__ A, const float* __restrict__ D,
                      const float* __restrict__ F, const float* __restrict__ lam2p,
                      float* __restrict__ FD, float* __restrict__ G,
                      float* __restrict__ AD) {
    int gid = blockIdx.x * 256 + threadIdx.x;
    if (gid < 65536) {                   // FD[k][j] = sum_q F[k][q] D[q][j]
        int k = gid >> 8, j = gid & 255;
        float s = 0.f;
        #pragma unroll 8
        for (int q = 0; q < 256; ++q) s += F[k*256+q] * D[q*256+j];
        FD[gid] = s;
    } else if (gid < 131072) {           // G[p][q] = sum_m A[m][p] A[m][q] + lam2*(p==q)
        int g = gid - 65536; int p = g >> 8, q = g & 255;
        float s = (p == q) ? lam2p[0] : 0.f;
        #pragma unroll 8
        for (int m = 0; m < 64; ++m) s += A[m*256+p] * A[m*256+q];
        G[g] = s;
    } else if (gid < 147456) {           // AD[m][i] = sum_k A[m][k] D[k][i]
        int g = gid - 131072; int m = g >> 8, i = g & 255;
        float s = 0.f;
        #pragma unroll 8
        for (int k = 0; k < 256; ++k) s += A[m*256+k] * D[k*256+i];
        AD[g] = s;
    }
}

__global__ void prep2(const float* __restrict__ A, const float* __restrict__ D,
                      const float* __restrict__ alphap,
                      const float* __restrict__ FD, const float* __restrict__ G,
                      const float* __restrict__ AD,
                      float* __restrict__ Pt, float* __restrict__ GD,
                      float* __restrict__ Wt) {
    int gid = blockIdx.x * 256 + threadIdx.x;
    float inva = 1.0f / alphap[0];
    if (gid < 65536) {                   // Pt[j][i] = sum_k D[k][i] FD[k][j]
        int j = gid >> 8, i = gid & 255;
        float s = 0.f;
        #pragma unroll 8
        for (int k = 0; k < 256; ++k) s += D[k*256+i] * FD[k*256+j];
        Pt[gid] = s;
    } else if (gid < 131072) {           // GD[k][j] = sum_q G[k][q] D[q][j]
        int g = gid - 65536; int k = g >> 8, j = g & 255;
        float s = 0.f;
        #pragma unroll 8
        for (int q = 0; q < 256; ++q) s += G[k*256+q] * D[q*256+j];
        GD[g] = s;
    } else {                             // Wt[d][i] = inva * sum_m AD[m][i] A[m][d]
        int g = gid - 131072; int d = g >> 8, i = g & 255;
        float s = 0.f;
        #pragma unroll 8
        for (int m = 0; m < 64; ++m) s += AD[m*256+i] * A[m*256+d];
        Wt[g] = inva * s;
    }
}

__global__ void prep3(const float* __restrict__ D, const float* __restrict__ GD,
                      const float* __restrict__ alphap, float* __restrict__ St) {
    int gid = blockIdx.x * 256 + threadIdx.x;   // 65536 threads
    int j = gid >> 8, i = gid & 255;
    float inva = 1.0f / alphap[0];
    float s = 0.f;
    #pragma unroll 8
    for (int k = 0; k < 256; ++k) s += D[k*256+i] * GD[k*256+j];
    St[gid] = ((i == j) ? 1.0f : 0.0f) - inva * s;
}

// Pack S and P as fp16 MFMA A-fragments for v_mfma_f32_16x16x32_f16.
// Fragment (tile tau in 0..15, kk in 0..7, lane l):
//   8 fp16 = M[row][k0..k0+8) with row = 16*tau + (l&15), k0 = 32*kk + 8*(l>>4)
// stored as uint4 at Sfrag[((tau*8+kk)*64 + l)*4].
__global__ void prep4(const float* __restrict__ St, const float* __restrict__ Pt,
                      u32* __restrict__ Sfrag, u32* __restrict__ Pfrag) {
    int gid = blockIdx.x * 256 + threadIdx.x;   // 16384 threads
    int idx = gid & 8191;
    int l   = idx & 63;
    int kk  = (idx >> 6) & 7;
    int tau = idx >> 9;
    int row = 16*tau + (l & 15);
    int k0  = 32*kk + 8*(l >> 4);
    const float* M = (gid < 8192) ? St : Pt;     // M[i][k] = Mt[k*256+i]
    u32* O = (gid < 8192) ? Sfrag : Pfrag;
    uint4 v;
    v.x = packh2(M[(k0+0)*256 + row], M[(k0+1)*256 + row]);
    v.y = packh2(M[(k0+2)*256 + row], M[(k0+3)*256 + row]);
    v.z = packh2(M[(k0+4)*256 + row], M[(k0+5)*256 + row]);
    v.w = packh2(M[(k0+6)*256 + row], M[(k0+7)*256 + row]);
    *(uint4*)&O[idx*4] = v;
}

// ---------------------------------------------------------------------------
// Z-GEMM: Z[b][t][i] = sum_d Wt[d*256+i] * y[b][d][t], written PACKED fp16:
//   Zh[(b*256+t)*128 + i/2] = (Z[b][t][i_even], Z[b][t][i_even+1])
// ---------------------------------------------------------------------------
__launch_bounds__(256, 2)
__global__ void zgemm(const float* __restrict__ y, const float* __restrict__ Wt,
                      u32* __restrict__ Zh) {
    __shared__ float ys[64][132];    // [dd][tt]
    __shared__ float wsh[64][132];   // [dd][ii]
    const int b  = blockIdx.x;
    const int t0 = (blockIdx.y & 1) * 128;
    const int i0 = (blockIdx.y >> 1) * 128;
    const int tid = threadIdx.x;
    const int tx = tid & 15;   // i-octet
    const int ty = tid >> 4;   // t-octet
    float acc[8][8];           // [c=t][a=i]
    #pragma unroll
    for (int c = 0; c < 8; ++c)
        #pragma unroll
        for (int a = 0; a < 8; ++a) acc[c][a] = 0.f;

    for (int dc = 0; dc < 256; dc += 64) {
        #pragma unroll
        for (int k = 0; k < 8; ++k) {
            int idx = k * 256 + tid;
            int row = idx >> 5, col4 = idx & 31;
            float4 yv = *(const float4*)&y[((size_t)b*256 + dc + row)*256 + t0 + col4*4];
            float4 wv = *(const float4*)&Wt[(size_t)(dc + row)*256 + i0 + col4*4];
            *(float4*)&ys[row][col4*4]  = yv;
            *(float4*)&wsh[row][col4*4] = wv;
        }
        __syncthreads();
        #pragma unroll 4
        for (int dd = 0; dd < 64; ++dd) {
            float4 w0 = *(const float4*)&wsh[dd][8*tx];
            float4 w1 = *(const float4*)&wsh[dd][8*tx+4];
            float4 y0 = *(const float4*)&ys[dd][8*ty];
            float4 y1 = *(const float4*)&ys[dd][8*ty+4];
            float wv[8] = {w0.x,w0.y,w0.z,w0.w,w1.x,w1.y,w1.z,w1.w};
            float yv[8] = {y0.x,y0.y,y0.z,y0.w,y1.x,y1.y,y1.z,y1.w};
            #pragma unroll
            for (int c = 0; c < 8; ++c)
                #pragma unroll
                for (int a = 0; a < 8; ++a) acc[c][a] += wv[a] * yv[c];
        }
        __syncthreads();
    }
    #pragma unroll
    for (int c = 0; c < 8; ++c) {
        int t = t0 + 8*ty + c;
        uint4 pk;
        pk.x = packh2(acc[c][0], acc[c][1]);
        pk.y = packh2(acc[c][2], acc[c][3]);
        pk.z = packh2(acc[c][4], acc[c][5]);
        pk.w = packh2(acc[c][6], acc[c][7]);
        *(uint4*)&Zh[((size_t)b*256 + t)*128 + (i0 >> 1) + 4*tx] = pk;
    }
}

// ---------------------------------------------------------------------------
// scan8: MFMA scan, scan6 structure (plain __syncthreads, depth-8 chains)
// with issue-point reordering so vmcnt drains at barriers expose nothing:
//  - Z prefetch for t+1 issued AFTER the P-barrier (drains ~1 round later)
//  - H store issued AFTER the iter-3 barrier (drains at next P-barrier)
//  - const vector computed AFTER the P-barrier (hides under iter-0 ds_reads)
// 16 blocks x 512 threads; block = 16 batches, wave w owns rows 32w..32w+31.
// Per round: 8 ds_read_b128 of h B-frags + 16 MFMA (2 depth-8 chains).
// ---------------------------------------------------------------------------
__global__ __attribute__((amdgpu_flat_work_group_size(512, 512),
                          amdgpu_waves_per_eu(2, 2)))
void scan8(const u32* __restrict__ Sfrag, const u32* __restrict__ Pfrag,
           const u32* __restrict__ Zh,
           const float* __restrict__ h0, const float* __restrict__ U,
           const float* __restrict__ lam1p, const float* __restrict__ lam2p,
           const float* __restrict__ alphap,
           float* __restrict__ H) {
    __shared__ __align__(16) u32 hx[2 * 2048];   // 2 x 8 KB h B-fragment buffers

    const int tid = threadIdx.x;
    const int l   = tid & 63;
    const int w   = tid >> 6;          // wave 0..7
    const int lb  = l & 15;            // batch-in-group == MFMA col
    const int g   = l >> 4;            // 0..3
    const int b   = blockIdx.x * 16 + lb;

    const float inva = 1.0f / alphap[0];
    const float bt   = lam1p[0] * inva;
    const float c2   = lam2p[0] * inva;

    // per-lane rows: 32w + 16T + 4g + r
    const int rb = 32*w + 4*g;
    const float u00 = U[rb+0]*bt,  u01 = U[rb+1]*bt,  u02 = U[rb+2]*bt,  u03 = U[rb+3]*bt;
    const float u10 = U[rb+16]*bt, u11 = U[rb+17]*bt, u12 = U[rb+18]*bt, u13 = U[rb+19]*bt;

    // A-fragments -> (A)GPRs (coalesced uint4 loads)
    f16x8 Sf0[8], Sf1[8], Pf0[8], Pf1[8];
    #pragma unroll
    for (int kk = 0; kk < 8; ++kk) {
        Sf0[kk] = __builtin_bit_cast(f16x8, *(const uint4*)&Sfrag[(((2*w+0)*8 + kk)*64 + l)*4]);
        Sf1[kk] = __builtin_bit_cast(f16x8, *(const uint4*)&Sfrag[(((2*w+1)*8 + kk)*64 + l)*4]);
        Pf0[kk] = __builtin_bit_cast(f16x8, *(const uint4*)&Pfrag[(((2*w+0)*8 + kk)*64 + l)*4]);
        Pf1[kk] = __builtin_bit_cast(f16x8, *(const uint4*)&Pfrag[(((2*w+1)*8 + kk)*64 + l)*4]);
    }

    // init h_prev B-fragments (h0 is batch-independent: value depends on k only)
    {
        int k0 = 32*(tid >> 6) + 8*((tid & 63) >> 4);
        uint4 hv;
        hv.x = packh2(h0[k0+0], h0[k0+1]);
        hv.y = packh2(h0[k0+2], h0[k0+3]);
        hv.z = packh2(h0[k0+4], h0[k0+5]);
        hv.w = packh2(h0[k0+6], h0[k0+7]);
        *(uint4*)&hx[tid*4] = hv;
    }
    __syncthreads();

    // Z: uint2 at Zb[t*128 + 8T] covers i = 32w + 16T + 4g + {0..3}
    const u32* Zb = Zh + (size_t)b*32768 + 16*w + 2*g;
    float* Hb = H + (size_t)b*TLEN*DIMN + 32*w + 4*g;

    // write slot (u32 index inside a buffer) for this lane's tile-T=0 pair;
    // tile-T=1 is +128.  (kk = w slice; lane'' = (2T + (g>>1))*16 + lb)
    const int wb0 = w*256 + (((g>>1))*16 + lb)*4 + (g&1)*2;

    int ro = 0, wo = 2048;

    uint2 z0 = *(const uint2*)&Zb[0];
    uint2 z1 = *(const uint2*)&Zb[8];

    #pragma unroll 1
    for (int t = 0; t < TLEN; ++t) {
        // ---- P-phase: ph = P @ h_prev ----
        f16x8 hb[8];
        #pragma unroll
        for (int kk = 0; kk < 8; ++kk)
            hb[kk] = __builtin_bit_cast(f16x8, *(const uint4*)&hx[ro + (kk*64 + l)*4]);
        f32x4 a0 = {0.f,0.f,0.f,0.f}, a1 = {0.f,0.f,0.f,0.f};
        #pragma unroll
        for (int kk = 0; kk < 8; ++kk) {
            a0 = __builtin_amdgcn_mfma_f32_16x16x32_f16(Pf0[kk], hb[kk], a0, 0, 0, 0);
            a1 = __builtin_amdgcn_mfma_f32_16x16x32_f16(Pf1[kk], hb[kk], a1, 0, 0, 0);
        }
        // h_iter0 = Ph (unthresholded)
        *(uint2*)&hx[wo + wb0]       = make_uint2(packh2(a0[0],a0[1]), packh2(a0[2],a0[3]));
        *(uint2*)&hx[wo + wb0 + 128] = make_uint2(packh2(a1[0],a1[1]), packh2(a1[2],a1[3]));
        __syncthreads();

        // Z prefetch for t+1: issued right after a barrier, so the next
        // vmcnt(0) drain (iter-0 barrier) is ~1 round (>900cy) away.
        const int tn = (t < TLEN-1) ? t + 1 : t;
        uint2 zn0 = *(const uint2*)&Zb[(size_t)tn*128];
        uint2 zn1 = *(const uint2*)&Zb[(size_t)tn*128 + 8];

        // const vector (off pre-barrier critical path; hides under iter-0 reads)
        const float c00 = h2lo(z0.x) + c2*a0[0];
        const float c01 = h2hi(z0.x) + c2*a0[1];
        const float c02 = h2lo(z0.y) + c2*a0[2];
        const float c03 = h2hi(z0.y) + c2*a0[3];
        const float c10 = h2lo(z1.x) + c2*a1[0];
        const float c11 = h2hi(z1.x) + c2*a1[1];
        const float c12 = h2lo(z1.y) + c2*a1[2];
        const float c13 = h2hi(z1.y) + c2*a1[3];
        int rr = wo, ww = ro;

        // ---- 4 S-iterations: h = soft(S@h + const) ----
        #pragma unroll
        for (int it = 0; it < 4; ++it) {
            #pragma unroll
            for (int kk = 0; kk < 8; ++kk)
                hb[kk] = __builtin_bit_cast(f16x8, *(const uint4*)&hx[rr + (kk*64 + l)*4]);
            f32x4 s0 = {c00,c01,c02,c03};
            f32x4 s1 = {c10,c11,c12,c13};
            #pragma unroll
            for (int kk = 0; kk < 8; ++kk) {
                s0 = __builtin_amdgcn_mfma_f32_16x16x32_f16(Sf0[kk], hb[kk], s0, 0, 0, 0);
                s1 = __builtin_amdgcn_mfma_f32_16x16x32_f16(Sf1[kk], hb[kk], s1, 0, 0, 0);
            }
            // soft-threshold: copysign(max(|v|-u, 0), v)  (4 VALU, bit-identical)
            const float h00 = copysignf(fmaxf(fabsf(s0[0]) - u00, 0.f), s0[0]);
            const float h01 = copysignf(fmaxf(fabsf(s0[1]) - u01, 0.f), s0[1]);
            const float h02 = copysignf(fmaxf(fabsf(s0[2]) - u02, 0.f), s0[2]);
            const float h03 = copysignf(fmaxf(fabsf(s0[3]) - u03, 0.f), s0[3]);
            const float h10 = copysignf(fmaxf(fabsf(s1[0]) - u10, 0.f), s1[0]);
            const float h11 = copysignf(fmaxf(fabsf(s1[1]) - u11, 0.f), s1[1]);
            const float h12 = copysignf(fmaxf(fabsf(s1[2]) - u12, 0.f), s1[2]);
            const float h13 = copysignf(fmaxf(fabsf(s1[3]) - u13, 0.f), s1[3]);
            *(uint2*)&hx[ww + wb0]       = make_uint2(packh2(h00,h01), packh2(h02,h03));
            *(uint2*)&hx[ww + wb0 + 128] = make_uint2(packh2(h10,h11), packh2(h12,h13));
            __syncthreads();
            if (it == 3) {   // fire-and-forget after the barrier; drains at next P-barrier
                *(float4*)&Hb[(size_t)t*DIMN]      = make_float4(h00, h01, h02, h03);
                *(float4*)&Hb[(size_t)t*DIMN + 16] = make_float4(h10, h11, h12, h13);
            }
            int tmp = rr; rr = ww; ww = tmp;
        }
        ro = rr; wo = ww;     // rr holds final h_t -> next step's h_prev
        z0 = zn0; z1 = zn1;
    }
}

// ---------------------------------------------------------------------------
// out-GEMM: out[b][n][t] = sum_d D[n][d] * H[b][t][d]
// ---------------------------------------------------------------------------
__launch_bounds__(256, 2)
__global__ void ogemm(const float* __restrict__ D, const float* __restrict__ H,
                      float* __restrict__ out) {
    __shared__ float Ds[64][132];   // [dd][nn]
    __shared__ float Hs[64][132];   // [dd][tt]
    const int b  = blockIdx.x;
    const int n0 = (blockIdx.y & 1) * 128;
    const int t0 = (blockIdx.y >> 1) * 128;
    const int tid = threadIdx.x;
    const int tx = tid & 15;   // n-octet
    const int ty = tid >> 4;   // t-octet
    float acc[8][8];           // [a=n][c=t]
    #pragma unroll
    for (int a = 0; a < 8; ++a)
        #pragma unroll
        for (int c = 0; c < 8; ++c) acc[a][c] = 0.f;

    for (int dc = 0; dc < 256; dc += 64) {
        #pragma unroll
        for (int k = 0; k < 8; ++k) {
            int idx = k * 256 + tid;
            int row = idx >> 4;                // nn or tt (128 rows)
            int d4  = idx & 15;                // 16 float4 across d-chunk
            float4 dv = *(const float4*)&D[((size_t)(n0 + row))*256 + dc + d4*4];
            float4 hv = *(const float4*)&H[((size_t)b*256 + t0 + row)*256 + dc + d4*4];
            Ds[d4*4+0][row] = dv.x; Ds[d4*4+1][row] = dv.y;
            Ds[d4*4+2][row] = dv.z; Ds[d4*4+3][row] = dv.w;
            Hs[d4*4+0][row] = hv.x; Hs[d4*4+1][row] = hv.y;
            Hs[d4*4+2][row] = hv.z; Hs[d4*4+3][row] = hv.w;
        }
        __syncthreads();
        #pragma unroll 4
        for (int dd = 0; dd < 64; ++dd) {
            float4 d0 = *(const float4*)&Ds[dd][8*tx];
            float4 d1 = *(const float4*)&Ds[dd][8*tx+4];
            float4 h0v = *(const float4*)&Hs[dd][8*ty];
            float4 h1v = *(const float4*)&Hs[dd][8*ty+4];
            float dv[8] = {d0.x,d0.y,d0.z,d0.w,d1.x,d1.y,d1.z,d1.w};
            float hv[8] = {h0v.x,h0v.y,h0v.z,h0v.w,h1v.x,h1v.y,h1v.z,h1v.w};
            #pragma unroll
            for (int a = 0; a < 8; ++a)
                #pragma unroll
                for (int c = 0; c < 8; ++c) acc[a][c] += dv[a] * hv[c];
        }
        __syncthreads();
    }
    #pragma unroll
    for (int a = 0; a < 8; ++a) {
        float* op = &out[((size_t)b*256 + n0 + 8*tx + a)*256 + t0 + 8*ty];
        *(float4*)(op)     = make_float4(acc[a][0], acc[a][1], acc[a][2], acc[a][3]);
        *(float4*)(op + 4) = make_float4(acc[a][4], acc[a][5], acc[a][6], acc[a][7]);
    }
}

// ---------------------------------------------------------------------------
extern "C" void kernel_launch(void* const* d_in, const int* in_sizes, int n_in,
                              void* d_out, int out_size, void* d_ws, size_t ws_size,
                              hipStream_t stream) {
    const float* y     = (const float*)d_in[0];
    const float* A     = (const float*)d_in[1];
    const float* D     = (const float*)d_in[2];
    const float* F     = (const float*)d_in[3];
    const float* lam1  = (const float*)d_in[4];
    const float* lam2  = (const float*)d_in[5];
    const float* alpha = (const float*)d_in[6];
    const float* h0    = (const float*)d_in[7];
    const float* U     = (const float*)d_in[8];
    float* out = (float*)d_out;
    float* ws  = (float*)d_ws;

    // ws layout (fp32-element offsets)
    const size_t oZ  = 0;           // Zh: 8.39M u32 packed fp16 (region 16.7M)
    const size_t oH  = 16777216;    // H fp32: 16.7M
    const size_t oWt = 33554432;
    const size_t oSt = 33619968;
    const size_t oPt = 33685504;
    const size_t oFD = 33751040;
    const size_t oG  = 33816576;
    const size_t oGD = 33882112;
    const size_t oAD = 33947648;
    const size_t oSh = 33964032;   // Sfrag u32 (32768)
    const size_t oPh = 33996800;   // Pfrag u32 (32768)

    u32*   Zh = (u32*)(ws + oZ);
    float* H  = ws + oH;
    float* Wt = ws + oWt; float* St = ws + oSt; float* Pt = ws + oPt;
    float* FD = ws + oFD; float* G  = ws + oG;  float* GD = ws + oGD;
    float* AD = ws + oAD;
    u32* Sfrag = (u32*)(ws + oSh);
    u32* Pfrag = (u32*)(ws + oPh);

    prep1<<<576, 256, 0, stream>>>(A, D, F, lam2, FD, G, AD);
    prep2<<<768, 256, 0, stream>>>(A, D, alpha, FD, G, AD, Pt, GD, Wt);
    prep3<<<256, 256, 0, stream>>>(D, GD, alpha, St);
    prep4<<<64, 256, 0, stream>>>(St, Pt, Sfrag, Pfrag);
    {
        dim3 g(256, 4);
        zgemm<<<g, 256, 0, stream>>>(y, Wt, Zh);
    }
    scan8<<<16, 512, 0, stream>>>(Sfrag, Pfrag, Zh, h0, U, lam1, lam2, alpha, H);
    {
        dim3 g(256, 4);
        ogemm<<<g, 256, 0, stream>>>(D, H, out);
    }
}

// Round 4
// 950.485 us; speedup vs baseline: 1.1097x; 1.0438x over previous
//
#include <hip/hip_runtime.h>
#include <hip/hip_bf16.h>

typedef unsigned int u32;
typedef unsigned short u16;

#define DIMN 256
#define TLEN 256

// ---------------------------------------------------------------------------
// helpers
// ---------------------------------------------------------------------------
typedef _Float16 half2v __attribute__((ext_vector_type(2)));
typedef _Float16 f16x8  __attribute__((ext_vector_type(8)));
typedef float    f32x4  __attribute__((ext_vector_type(4)));

__device__ __forceinline__ u32 packh2(float lo, float hi) {
    _Float16 l = (_Float16)lo, h = (_Float16)hi;
    u16 lu = __builtin_bit_cast(u16, l);
    u16 hu = __builtin_bit_cast(u16, h);
    return (u32)lu | ((u32)hu << 16);
}

__device__ __forceinline__ float h2lo(u32 v) {
    return (float)__builtin_bit_cast(half2v, v).x;
}
__device__ __forceinline__ float h2hi(u32 v) {
    return (float)__builtin_bit_cast(half2v, v).y;
}

// ---------------------------------------------------------------------------
// prep kernels: build P^T, S^T, W^T, Q^T (fp32), then pack S/P/Q as MFMA
// A-fragments.
//   Pt[j*256+i] = P[i][j],  P = D^T F D
//   St[j*256+i] = S[i][j],  S = I - (1/a) D^T (A^T A + lam2 I) D
//   Wt[d*256+i] = W[i][d],  W = (1/a) D^T A^T A
//   Qt[j*256+i] = Q[i][j],  Q = (S + c2 I) P   (fuses P-phase with iter-0)
// ---------------------------------------------------------------------------
__global__ void prep1(const float* __restrict__ A, const float* __restrict__ D,
                      const float* __restrict__ F, const float* __restrict__ lam2p,
                      float* __restrict__ FD, float* __restrict__ G,
                      float* __restrict__ AD) {
    int gid = blockIdx.x * 256 + threadIdx.x;
    if (gid < 65536) {                   // FD[k][j] = sum_q F[k][q] D[q][j]
        int k = gid >> 8, j = gid & 255;
        float s = 0.f;
        #pragma unroll 8
        for (int q = 0; q < 256; ++q) s += F[k*256+q] * D[q*256+j];
        FD[gid] = s;
    } else if (gid < 131072) {           // G[p][q] = sum_m A[m][p] A[m][q] + lam2*(p==q)
        int g = gid - 65536; int p = g >> 8, q = g & 255;
        float s = (p == q) ? lam2p[0] : 0.f;
        #pragma unroll 8
        for (int m = 0; m < 64; ++m) s += A[m*256+p] * A[m*256+q];
        G[g] = s;
    } else if (gid < 147456) {           // AD[m][i] = sum_k A[m][k] D[k][i]
        int g = gid - 131072; int m = g >> 8, i = g & 255;
        float s = 0.f;
        #pragma unroll 8
        for (int k = 0; k < 256; ++k) s += A[m*256+k] * D[k*256+i];
        AD[g] = s;
    }
}

__global__ void prep2(const float* __restrict__ A, const float* __restrict__ D,
                      const float* __restrict__ alphap,
                      const float* __restrict__ FD, const float* __restrict__ G,
                      const float* __restrict__ AD,
                      float* __restrict__ Pt, float* __restrict__ GD,
                      float* __restrict__ Wt) {
    int gid = blockIdx.x * 256 + threadIdx.x;
    float inva = 1.0f / alphap[0];
    if (gid < 65536) {                   // Pt[j][i] = sum_k D[k][i] FD[k][j]
        int j = gid >> 8, i = gid & 255;
        float s = 0.f;
        #pragma unroll 8
        for (int k = 0; k < 256; ++k) s += D[k*256+i] * FD[k*256+j];
        Pt[gid] = s;
    } else if (gid < 131072) {           // GD[k][j] = sum_q G[k][q] D[q][j]
        int g = gid - 65536; int k = g >> 8, j = g & 255;
        float s = 0.f;
        #pragma unroll 8
        for (int q = 0; q < 256; ++q) s += G[k*256+q] * D[q*256+j];
        GD[g] = s;
    } else {                             // Wt[d][i] = inva * sum_m AD[m][i] A[m][d]
        int g = gid - 131072; int d = g >> 8, i = g & 255;
        float s = 0.f;
        #pragma unroll 8
        for (int m = 0; m < 64; ++m) s += AD[m*256+i] * A[m*256+d];
        Wt[g] = inva * s;
    }
}

__global__ void prep3(const float* __restrict__ D, const float* __restrict__ GD,
                      const float* __restrict__ alphap, float* __restrict__ St) {
    int gid = blockIdx.x * 256 + threadIdx.x;   // 65536 threads
    int j = gid >> 8, i = gid & 255;
    float inva = 1.0f / alphap[0];
    float s = 0.f;
    #pragma unroll 8
    for (int k = 0; k < 256; ++k) s += D[k*256+i] * GD[k*256+j];
    St[gid] = ((i == j) ? 1.0f : 0.0f) - inva * s;
}

// Q = (S + c2 I) P :  Q[i][j] = sum_k S[i][k] P[k][j] + c2 * P[i][j]
// stored transposed: Qt[j*256+i] = Q[i][j]
__global__ void prep5(const float* __restrict__ St, const float* __restrict__ Pt,
                      const float* __restrict__ lam2p, const float* __restrict__ alphap,
                      float* __restrict__ Qt) {
    int gid = blockIdx.x * 256 + threadIdx.x;   // 65536 threads
    int j = gid >> 8, i = gid & 255;
    float c2 = lam2p[0] / alphap[0];
    float s = c2 * Pt[j*256 + i];
    #pragma unroll 8
    for (int k = 0; k < 256; ++k) s += St[k*256+i] * Pt[j*256+k];
    Qt[gid] = s;
}

// Pack S, P, Q as fp16 MFMA A-fragments for v_mfma_f32_16x16x32_f16.
// Fragment (tile tau in 0..15, kk in 0..7, lane l):
//   8 fp16 = M[row][k0..k0+8) with row = 16*tau + (l&15), k0 = 32*kk + 8*(l>>4)
// stored as uint4 at frag[((tau*8+kk)*64 + l)*4].
__global__ void prep4(const float* __restrict__ St, const float* __restrict__ Pt,
                      const float* __restrict__ Qt,
                      u32* __restrict__ Sfrag, u32* __restrict__ Pfrag,
                      u32* __restrict__ Qfrag) {
    int gid = blockIdx.x * 256 + threadIdx.x;   // 24576 threads
    int sel = gid >> 13;
    int idx = gid & 8191;
    int l   = idx & 63;
    int kk  = (idx >> 6) & 7;
    int tau = idx >> 9;
    int row = 16*tau + (l & 15);
    int k0  = 32*kk + 8*(l >> 4);
    const float* M = (sel == 0) ? St : (sel == 1) ? Pt : Qt;   // M[i][k] = Mt[k*256+i]
    u32* O = (sel == 0) ? Sfrag : (sel == 1) ? Pfrag : Qfrag;
    uint4 v;
    v.x = packh2(M[(k0+0)*256 + row], M[(k0+1)*256 + row]);
    v.y = packh2(M[(k0+2)*256 + row], M[(k0+3)*256 + row]);
    v.z = packh2(M[(k0+4)*256 + row], M[(k0+5)*256 + row]);
    v.w = packh2(M[(k0+6)*256 + row], M[(k0+7)*256 + row]);
    *(uint4*)&O[idx*4] = v;
}

// ---------------------------------------------------------------------------
// Z-GEMM: Z[b][t][i] = sum_d Wt[d*256+i] * y[b][d][t], written PACKED fp16:
//   Zh[(b*256+t)*128 + i/2] = (Z[b][t][i_even], Z[b][t][i_even+1])
// ---------------------------------------------------------------------------
__launch_bounds__(256, 2)
__global__ void zgemm(const float* __restrict__ y, const float* __restrict__ Wt,
                      u32* __restrict__ Zh) {
    __shared__ float ys[64][132];    // [dd][tt]
    __shared__ float wsh[64][132];   // [dd][ii]
    const int b  = blockIdx.x;
    const int t0 = (blockIdx.y & 1) * 128;
    const int i0 = (blockIdx.y >> 1) * 128;
    const int tid = threadIdx.x;
    const int tx = tid & 15;   // i-octet
    const int ty = tid >> 4;   // t-octet
    float acc[8][8];           // [c=t][a=i]
    #pragma unroll
    for (int c = 0; c < 8; ++c)
        #pragma unroll
        for (int a = 0; a < 8; ++a) acc[c][a] = 0.f;

    for (int dc = 0; dc < 256; dc += 64) {
        #pragma unroll
        for (int k = 0; k < 8; ++k) {
            int idx = k * 256 + tid;
            int row = idx >> 5, col4 = idx & 31;
            float4 yv = *(const float4*)&y[((size_t)b*256 + dc + row)*256 + t0 + col4*4];
            float4 wv = *(const float4*)&Wt[(size_t)(dc + row)*256 + i0 + col4*4];
            *(float4*)&ys[row][col4*4]  = yv;
            *(float4*)&wsh[row][col4*4] = wv;
        }
        __syncthreads();
        #pragma unroll 4
        for (int dd = 0; dd < 64; ++dd) {
            float4 w0 = *(const float4*)&wsh[dd][8*tx];
            float4 w1 = *(const float4*)&wsh[dd][8*tx+4];
            float4 y0 = *(const float4*)&ys[dd][8*ty];
            float4 y1 = *(const float4*)&ys[dd][8*ty+4];
            float wv[8] = {w0.x,w0.y,w0.z,w0.w,w1.x,w1.y,w1.z,w1.w};
            float yv[8] = {y0.x,y0.y,y0.z,y0.w,y1.x,y1.y,y1.z,y1.w};
            #pragma unroll
            for (int c = 0; c < 8; ++c)
                #pragma unroll
                for (int a = 0; a < 8; ++a) acc[c][a] += wv[a] * yv[c];
        }
        __syncthreads();
    }
    #pragma unroll
    for (int c = 0; c < 8; ++c) {
        int t = t0 + 8*ty + c;
        uint4 pk;
        pk.x = packh2(acc[c][0], acc[c][1]);
        pk.y = packh2(acc[c][2], acc[c][3]);
        pk.z = packh2(acc[c][4], acc[c][5]);
        pk.w = packh2(acc[c][6], acc[c][7]);
        *(uint4*)&Zh[((size_t)b*256 + t)*128 + (i0 >> 1) + 4*tx] = pk;
    }
}

// ---------------------------------------------------------------------------
// scan9: 4-round MFMA scan via Q-fusion.  Q = (S + c2 I) P folds the P-phase
// and iter-0 into one round:
//   round A: h1 = soft(Q h_prev + Z)   AND   const = Z + c2 * (P h_prev)
//            (two accumulator chains on the SAME hb fragments; the P result
//             stays in the owning lane's registers - no Ph LDS exchange)
//   rounds B,C,D: h = soft(S h + const);  D also stores H.
// 16 blocks x 512 threads; wave w owns rows 32w..32w+31 (tiles 2w, 2w+1).
// 4 barriers/step (was 5).  Buffers strictly alternate: A:rd0/wr1, B:rd1/wr0,
// C:rd0/wr1, D:rd1/wr0 -> next step reads buf0 again.
// ---------------------------------------------------------------------------
__global__ __attribute__((amdgpu_flat_work_group_size(512, 512),
                          amdgpu_waves_per_eu(2, 2)))
void scan9(const u32* __restrict__ Sfrag, const u32* __restrict__ Pfrag,
           const u32* __restrict__ Qfrag,
           const u32* __restrict__ Zh,
           const float* __restrict__ h0, const float* __restrict__ U,
           const float* __restrict__ lam1p, const float* __restrict__ lam2p,
           const float* __restrict__ alphap,
           float* __restrict__ H) {
    __shared__ __align__(16) u32 hx[2 * 2048];   // 2 x 8 KB h B-fragment buffers

    const int tid = threadIdx.x;
    const int l   = tid & 63;
    const int w   = tid >> 6;          // wave 0..7
    const int lb  = l & 15;            // batch-in-group == MFMA col
    const int g   = l >> 4;            // 0..3
    const int b   = blockIdx.x * 16 + lb;

    const float inva = 1.0f / alphap[0];
    const float bt   = lam1p[0] * inva;
    const float c2   = lam2p[0] * inva;

    // per-lane rows: 32w + 16T + 4g + r
    const int rb = 32*w + 4*g;
    const float u00 = U[rb+0]*bt,  u01 = U[rb+1]*bt,  u02 = U[rb+2]*bt,  u03 = U[rb+3]*bt;
    const float u10 = U[rb+16]*bt, u11 = U[rb+17]*bt, u12 = U[rb+18]*bt, u13 = U[rb+19]*bt;

    // A-fragments -> AGPR-backed registers (coalesced uint4 loads)
    f16x8 Sf0[8], Sf1[8], Pf0[8], Pf1[8], Qf0[8], Qf1[8];
    #pragma unroll
    for (int kk = 0; kk < 8; ++kk) {
        Sf0[kk] = __builtin_bit_cast(f16x8, *(const uint4*)&Sfrag[(((2*w+0)*8 + kk)*64 + l)*4]);
        Sf1[kk] = __builtin_bit_cast(f16x8, *(const uint4*)&Sfrag[(((2*w+1)*8 + kk)*64 + l)*4]);
        Pf0[kk] = __builtin_bit_cast(f16x8, *(const uint4*)&Pfrag[(((2*w+0)*8 + kk)*64 + l)*4]);
        Pf1[kk] = __builtin_bit_cast(f16x8, *(const uint4*)&Pfrag[(((2*w+1)*8 + kk)*64 + l)*4]);
        Qf0[kk] = __builtin_bit_cast(f16x8, *(const uint4*)&Qfrag[(((2*w+0)*8 + kk)*64 + l)*4]);
        Qf1[kk] = __builtin_bit_cast(f16x8, *(const uint4*)&Qfrag[(((2*w+1)*8 + kk)*64 + l)*4]);
    }

    // init h_prev B-fragments into buf0 (h0 is batch-independent)
    {
        int k0 = 32*(tid >> 6) + 8*((tid & 63) >> 4);
        uint4 hv;
        hv.x = packh2(h0[k0+0], h0[k0+1]);
        hv.y = packh2(h0[k0+2], h0[k0+3]);
        hv.z = packh2(h0[k0+4], h0[k0+5]);
        hv.w = packh2(h0[k0+6], h0[k0+7]);
        *(uint4*)&hx[tid*4] = hv;
    }
    __syncthreads();

    // Z: uint2 at Zb[t*128 + 8T] covers i = 32w + 16T + 4g + {0..3}
    const u32* Zb = Zh + (size_t)b*32768 + 16*w + 2*g;
    float* Hb = H + (size_t)b*TLEN*DIMN + 32*w + 4*g;

    // write slot (u32 index inside a buffer) for this lane's tile-T=0 pair;
    // tile-T=1 is +128.  (kk = w slice; lane'' = (2T + (g>>1))*16 + lb)
    const int wb0 = w*256 + (((g>>1))*16 + lb)*4 + (g&1)*2;

    uint2 z0 = *(const uint2*)&Zb[0];
    uint2 z1 = *(const uint2*)&Zb[8];

    #pragma unroll 1
    for (int t = 0; t < TLEN; ++t) {
        // ---- Round A: q = Q h_prev (+Z init), a = P h_prev ----
        f16x8 hb[8];
        #pragma unroll
        for (int kk = 0; kk < 8; ++kk)
            hb[kk] = __builtin_bit_cast(f16x8, *(const uint4*)&hx[0 + (kk*64 + l)*4]);
        f32x4 q0 = {h2lo(z0.x), h2hi(z0.x), h2lo(z0.y), h2hi(z0.y)};
        f32x4 q1 = {h2lo(z1.x), h2hi(z1.x), h2lo(z1.y), h2hi(z1.y)};
        f32x4 a0 = {0.f,0.f,0.f,0.f}, a1 = {0.f,0.f,0.f,0.f};
        #pragma unroll
        for (int kk = 0; kk < 8; ++kk) {
            q0 = __builtin_amdgcn_mfma_f32_16x16x32_f16(Qf0[kk], hb[kk], q0, 0, 0, 0);
            q1 = __builtin_amdgcn_mfma_f32_16x16x32_f16(Qf1[kk], hb[kk], q1, 0, 0, 0);
            a0 = __builtin_amdgcn_mfma_f32_16x16x32_f16(Pf0[kk], hb[kk], a0, 0, 0, 0);
            a1 = __builtin_amdgcn_mfma_f32_16x16x32_f16(Pf1[kk], hb[kk], a1, 0, 0, 0);
        }
        // h1 = soft(q)
        {
            const float h00 = copysignf(fmaxf(fabsf(q0[0]) - u00, 0.f), q0[0]);
            const float h01 = copysignf(fmaxf(fabsf(q0[1]) - u01, 0.f), q0[1]);
            const float h02 = copysignf(fmaxf(fabsf(q0[2]) - u02, 0.f), q0[2]);
            const float h03 = copysignf(fmaxf(fabsf(q0[3]) - u03, 0.f), q0[3]);
            const float h10 = copysignf(fmaxf(fabsf(q1[0]) - u10, 0.f), q1[0]);
            const float h11 = copysignf(fmaxf(fabsf(q1[1]) - u11, 0.f), q1[1]);
            const float h12 = copysignf(fmaxf(fabsf(q1[2]) - u12, 0.f), q1[2]);
            const float h13 = copysignf(fmaxf(fabsf(q1[3]) - u13, 0.f), q1[3]);
            *(uint2*)&hx[2048 + wb0]       = make_uint2(packh2(h00,h01), packh2(h02,h03));
            *(uint2*)&hx[2048 + wb0 + 128] = make_uint2(packh2(h10,h11), packh2(h12,h13));
        }
        __syncthreads();

        // Z prefetch for t+1 (used ~4 rounds from now - fully hidden)
        const int tn = (t < TLEN-1) ? t + 1 : t;
        uint2 zn0 = *(const uint2*)&Zb[(size_t)tn*128];
        uint2 zn1 = *(const uint2*)&Zb[(size_t)tn*128 + 8];

        // const = Z + c2 * (P h_prev)  (off critical path; hides under B's reads)
        const float c00 = h2lo(z0.x) + c2*a0[0];
        const float c01 = h2hi(z0.x) + c2*a0[1];
        const float c02 = h2lo(z0.y) + c2*a0[2];
        const float c03 = h2hi(z0.y) + c2*a0[3];
        const float c10 = h2lo(z1.x) + c2*a1[0];
        const float c11 = h2hi(z1.x) + c2*a1[1];
        const float c12 = h2lo(z1.y) + c2*a1[2];
        const float c13 = h2hi(z1.y) + c2*a1[3];

        // ---- Rounds B,C,D: h = soft(S h + const) ----
        #pragma unroll
        for (int it = 0; it < 3; ++it) {
            const int rd = (it & 1) ? 0 : 2048;
            const int wr = (it & 1) ? 2048 : 0;
            #pragma unroll
            for (int kk = 0; kk < 8; ++kk)
                hb[kk] = __builtin_bit_cast(f16x8, *(const uint4*)&hx[rd + (kk*64 + l)*4]);
            f32x4 s0 = {c00,c01,c02,c03};
            f32x4 s1 = {c10,c11,c12,c13};
            #pragma unroll
            for (int kk = 0; kk < 8; ++kk) {
                s0 = __builtin_amdgcn_mfma_f32_16x16x32_f16(Sf0[kk], hb[kk], s0, 0, 0, 0);
                s1 = __builtin_amdgcn_mfma_f32_16x16x32_f16(Sf1[kk], hb[kk], s1, 0, 0, 0);
            }
            const float h00 = copysignf(fmaxf(fabsf(s0[0]) - u00, 0.f), s0[0]);
            const float h01 = copysignf(fmaxf(fabsf(s0[1]) - u01, 0.f), s0[1]);
            const float h02 = copysignf(fmaxf(fabsf(s0[2]) - u02, 0.f), s0[2]);
            const float h03 = copysignf(fmaxf(fabsf(s0[3]) - u03, 0.f), s0[3]);
            const float h10 = copysignf(fmaxf(fabsf(s1[0]) - u10, 0.f), s1[0]);
            const float h11 = copysignf(fmaxf(fabsf(s1[1]) - u11, 0.f), s1[1]);
            const float h12 = copysignf(fmaxf(fabsf(s1[2]) - u12, 0.f), s1[2]);
            const float h13 = copysignf(fmaxf(fabsf(s1[3]) - u13, 0.f), s1[3]);
            *(uint2*)&hx[wr + wb0]       = make_uint2(packh2(h00,h01), packh2(h02,h03));
            *(uint2*)&hx[wr + wb0 + 128] = make_uint2(packh2(h10,h11), packh2(h12,h13));
            __syncthreads();
            if (it == 2) {   // fire-and-forget; drains during next step's round A
                *(float4*)&Hb[(size_t)t*DIMN]      = make_float4(h00, h01, h02, h03);
                *(float4*)&Hb[(size_t)t*DIMN + 16] = make_float4(h10, h11, h12, h13);
            }
        }
        z0 = zn0; z1 = zn1;
    }
}

// ---------------------------------------------------------------------------
// out-GEMM: out[b][n][t] = sum_d D[n][d] * H[b][t][d]
// ---------------------------------------------------------------------------
__launch_bounds__(256, 2)
__global__ void ogemm(const float* __restrict__ D, const float* __restrict__ H,
                      float* __restrict__ out) {
    __shared__ float Ds[64][132];   // [dd][nn]
    __shared__ float Hs[64][132];   // [dd][tt]
    const int b  = blockIdx.x;
    const int n0 = (blockIdx.y & 1) * 128;
    const int t0 = (blockIdx.y >> 1) * 128;
    const int tid = threadIdx.x;
    const int tx = tid & 15;   // n-octet
    const int ty = tid >> 4;   // t-octet
    float acc[8][8];           // [a=n][c=t]
    #pragma unroll
    for (int a = 0; a < 8; ++a)
        #pragma unroll
        for (int c = 0; c < 8; ++c) acc[a][c] = 0.f;

    for (int dc = 0; dc < 256; dc += 64) {
        #pragma unroll
        for (int k = 0; k < 8; ++k) {
            int idx = k * 256 + tid;
            int row = idx >> 4;                // nn or tt (128 rows)
            int d4  = idx & 15;                // 16 float4 across d-chunk
            float4 dv = *(const float4*)&D[((size_t)(n0 + row))*256 + dc + d4*4];
            float4 hv = *(const float4*)&H[((size_t)b*256 + t0 + row)*256 + dc + d4*4];
            Ds[d4*4+0][row] = dv.x; Ds[d4*4+1][row] = dv.y;
            Ds[d4*4+2][row] = dv.z; Ds[d4*4+3][row] = dv.w;
            Hs[d4*4+0][row] = hv.x; Hs[d4*4+1][row] = hv.y;
            Hs[d4*4+2][row] = hv.z; Hs[d4*4+3][row] = hv.w;
        }
        __syncthreads();
        #pragma unroll 4
        for (int dd = 0; dd < 64; ++dd) {
            float4 d0 = *(const float4*)&Ds[dd][8*tx];
            float4 d1 = *(const float4*)&Ds[dd][8*tx+4];
            float4 h0v = *(const float4*)&Hs[dd][8*ty];
            float4 h1v = *(const float4*)&Hs[dd][8*ty+4];
            float dv[8] = {d0.x,d0.y,d0.z,d0.w,d1.x,d1.y,d1.z,d1.w};
            float hv[8] = {h0v.x,h0v.y,h0v.z,h0v.w,h1v.x,h1v.y,h1v.z,h1v.w};
            #pragma unroll
            for (int a = 0; a < 8; ++a)
                #pragma unroll
                for (int c = 0; c < 8; ++c) acc[a][c] += dv[a] * hv[c];
        }
        __syncthreads();
    }
    #pragma unroll
    for (int a = 0; a < 8; ++a) {
        float* op = &out[((size_t)b*256 + n0 + 8*tx + a)*256 + t0 + 8*ty];
        *(float4*)(op)     = make_float4(acc[a][0], acc[a][1], acc[a][2], acc[a][3]);
        *(float4*)(op + 4) = make_float4(acc[a][4], acc[a][5], acc[a][6], acc[a][7]);
    }
}

// ---------------------------------------------------------------------------
extern "C" void kernel_launch(void* const* d_in, const int* in_sizes, int n_in,
                              void* d_out, int out_size, void* d_ws, size_t ws_size,
                              hipStream_t stream) {
    const float* y     = (const float*)d_in[0];
    const float* A     = (const float*)d_in[1];
    const float* D     = (const float*)d_in[2];
    const float* F     = (const float*)d_in[3];
    const float* lam1  = (const float*)d_in[4];
    const float* lam2  = (const float*)d_in[5];
    const float* alpha = (const float*)d_in[6];
    const float* h0    = (const float*)d_in[7];
    const float* U     = (const float*)d_in[8];
    float* out = (float*)d_out;
    float* ws  = (float*)d_ws;

    // ws layout (fp32-element offsets)
    const size_t oZ  = 0;           // Zh: 8.39M u32 packed fp16 (region 16.7M)
    const size_t oH  = 16777216;    // H fp32: 16.7M
    const size_t oWt = 33554432;
    const size_t oSt = 33619968;
    const size_t oPt = 33685504;
    const size_t oFD = 33751040;    // FD during prep1/2; Qt afterwards (65536)
    const size_t oG  = 33816576;    // G during prep1/2; Qfrag afterwards (32768 u32)
    const size_t oGD = 33882112;
    const size_t oAD = 33947648;
    const size_t oSh = 33964032;   // Sfrag u32 (32768)
    const size_t oPh = 33996800;   // Pfrag u32 (32768)

    u32*   Zh = (u32*)(ws + oZ);
    float* H  = ws + oH;
    float* Wt = ws + oWt; float* St = ws + oSt; float* Pt = ws + oPt;
    float* FD = ws + oFD; float* G  = ws + oG;  float* GD = ws + oGD;
    float* AD = ws + oAD;
    float* Qt = ws + oFD;            // reuse FD region (dead after prep2)
    u32* Sfrag = (u32*)(ws + oSh);
    u32* Pfrag = (u32*)(ws + oPh);
    u32* Qfrag = (u32*)(ws + oG);    // reuse G region (dead after prep2)

    prep1<<<576, 256, 0, stream>>>(A, D, F, lam2, FD, G, AD);
    prep2<<<768, 256, 0, stream>>>(A, D, alpha, FD, G, AD, Pt, GD, Wt);
    prep3<<<256, 256, 0, stream>>>(D, GD, alpha, St);
    prep5<<<256, 256, 0, stream>>>(St, Pt, lam2, alpha, Qt);
    prep4<<<96, 256, 0, stream>>>(St, Pt, Qt, Sfrag, Pfrag, Qfrag);
    {
        dim3 g(256, 4);
        zgemm<<<g, 256, 0, stream>>>(y, Wt, Zh);
    }
    scan9<<<16, 512, 0, stream>>>(Sfrag, Pfrag, Qfrag, Zh, h0, U, lam1, lam2, alpha, H);
    {
        dim3 g(256, 4);
        ogemm<<<g, 256, 0, stream>>>(D, H, out);
    }
}

// Round 5
// 789.602 us; speedup vs baseline: 1.3358x; 1.2038x over previous
//
#include <hip/hip_runtime.h>
#include <hip/hip_bf16.h>

typedef unsigned int u32;
typedef unsigned short u16;

#define DIMN 256
#define TLEN 256

// ---------------------------------------------------------------------------
// helpers
// ---------------------------------------------------------------------------
typedef _Float16 half2v __attribute__((ext_vector_type(2)));
typedef _Float16 f16x8  __attribute__((ext_vector_type(8)));
typedef float    f32x4  __attribute__((ext_vector_type(4)));

__device__ __forceinline__ u32 packh2(float lo, float hi) {
    _Float16 l = (_Float16)lo, h = (_Float16)hi;
    u16 lu = __builtin_bit_cast(u16, l);
    u16 hu = __builtin_bit_cast(u16, h);
    return (u32)lu | ((u32)hu << 16);
}

__device__ __forceinline__ float h2lo(u32 v) {
    return (float)__builtin_bit_cast(half2v, v).x;
}
__device__ __forceinline__ float h2hi(u32 v) {
    return (float)__builtin_bit_cast(half2v, v).y;
}

// ---------------------------------------------------------------------------
// prep kernels: build P^T, S^T, W^T, Q^T (fp32), then pack S/P/Q/W/D as MFMA
// A-fragments.
//   Pt[j*256+i] = P[i][j],  P = D^T F D
//   St[j*256+i] = S[i][j],  S = I - (1/a) D^T (A^T A + lam2 I) D
//   Wt[d*256+i] = W[i][d],  W = (1/a) D^T A^T A
//   Qt[j*256+i] = Q[i][j],  Q = (S + c2 I) P   (fuses P-phase with iter-0)
// ---------------------------------------------------------------------------
__global__ void prep1(const float* __restrict__ A, const float* __restrict__ D,
                      const float* __restrict__ F, const float* __restrict__ lam2p,
                      float* __restrict__ FD, float* __restrict__ G,
                      float* __restrict__ AD) {
    int gid = blockIdx.x * 256 + threadIdx.x;
    if (gid < 65536) {                   // FD[k][j] = sum_q F[k][q] D[q][j]
        int k = gid >> 8, j = gid & 255;
        float s = 0.f;
        #pragma unroll 8
        for (int q = 0; q < 256; ++q) s += F[k*256+q] * D[q*256+j];
        FD[gid] = s;
    } else if (gid < 131072) {           // G[p][q] = sum_m A[m][p] A[m][q] + lam2*(p==q)
        int g = gid - 65536; int p = g >> 8, q = g & 255;
        float s = (p == q) ? lam2p[0] : 0.f;
        #pragma unroll 8
        for (int m = 0; m < 64; ++m) s += A[m*256+p] * A[m*256+q];
        G[g] = s;
    } else if (gid < 147456) {           // AD[m][i] = sum_k A[m][k] D[k][i]
        int g = gid - 131072; int m = g >> 8, i = g & 255;
        float s = 0.f;
        #pragma unroll 8
        for (int k = 0; k < 256; ++k) s += A[m*256+k] * D[k*256+i];
        AD[g] = s;
    }
}

__global__ void prep2(const float* __restrict__ A, const float* __restrict__ D,
                      const float* __restrict__ alphap,
                      const float* __restrict__ FD, const float* __restrict__ G,
                      const float* __restrict__ AD,
                      float* __restrict__ Pt, float* __restrict__ GD,
                      float* __restrict__ Wt) {
    int gid = blockIdx.x * 256 + threadIdx.x;
    float inva = 1.0f / alphap[0];
    if (gid < 65536) {                   // Pt[j][i] = sum_k D[k][i] FD[k][j]
        int j = gid >> 8, i = gid & 255;
        float s = 0.f;
        #pragma unroll 8
        for (int k = 0; k < 256; ++k) s += D[k*256+i] * FD[k*256+j];
        Pt[gid] = s;
    } else if (gid < 131072) {           // GD[k][j] = sum_q G[k][q] D[q][j]
        int g = gid - 65536; int k = g >> 8, j = g & 255;
        float s = 0.f;
        #pragma unroll 8
        for (int q = 0; q < 256; ++q) s += G[k*256+q] * D[q*256+j];
        GD[g] = s;
    } else {                             // Wt[d][i] = inva * sum_m AD[m][i] A[m][d]
        int g = gid - 131072; int d = g >> 8, i = g & 255;
        float s = 0.f;
        #pragma unroll 8
        for (int m = 0; m < 64; ++m) s += AD[m*256+i] * A[m*256+d];
        Wt[g] = inva * s;
    }
}

__global__ void prep3(const float* __restrict__ D, const float* __restrict__ GD,
                      const float* __restrict__ alphap, float* __restrict__ St) {
    int gid = blockIdx.x * 256 + threadIdx.x;   // 65536 threads
    int j = gid >> 8, i = gid & 255;
    float inva = 1.0f / alphap[0];
    float s = 0.f;
    #pragma unroll 8
    for (int k = 0; k < 256; ++k) s += D[k*256+i] * GD[k*256+j];
    St[gid] = ((i == j) ? 1.0f : 0.0f) - inva * s;
}

// Q = (S + c2 I) P :  Q[i][j] = sum_k S[i][k] P[k][j] + c2 * P[i][j]
// stored transposed: Qt[j*256+i] = Q[i][j]
__global__ void prep5(const float* __restrict__ St, const float* __restrict__ Pt,
                      const float* __restrict__ lam2p, const float* __restrict__ alphap,
                      float* __restrict__ Qt) {
    int gid = blockIdx.x * 256 + threadIdx.x;   // 65536 threads
    int j = gid >> 8, i = gid & 255;
    float c2 = lam2p[0] / alphap[0];
    float s = c2 * Pt[j*256 + i];
    #pragma unroll 8
    for (int k = 0; k < 256; ++k) s += St[k*256+i] * Pt[j*256+k];
    Qt[gid] = s;
}

// Pack S, P, Q, W as fp16 MFMA A-fragments for v_mfma_f32_16x16x32_f16.
// Fragment (tile tau in 0..15, kk in 0..7, lane l):
//   8 fp16 = M[row][k0..k0+8) with row = 16*tau + (l&15), k0 = 32*kk + 8*(l>>4)
// stored as uint4 at frag[((tau*8+kk)*64 + l)*4].  Sources are transposed:
// M[i][k] = Mt[k*256+i].
__global__ void prep4(const float* __restrict__ St, const float* __restrict__ Pt,
                      const float* __restrict__ Qt, const float* __restrict__ Wt,
                      u32* __restrict__ Sfrag, u32* __restrict__ Pfrag,
                      u32* __restrict__ Qfrag, u32* __restrict__ Wfrag) {
    int gid = blockIdx.x * 256 + threadIdx.x;   // 32768 threads
    int sel = gid >> 13;
    int idx = gid & 8191;
    int l   = idx & 63;
    int kk  = (idx >> 6) & 7;
    int tau = idx >> 9;
    int row = 16*tau + (l & 15);
    int k0  = 32*kk + 8*(l >> 4);
    const float* M = (sel == 0) ? St : (sel == 1) ? Pt : (sel == 2) ? Qt : Wt;
    u32* O = (sel == 0) ? Sfrag : (sel == 1) ? Pfrag : (sel == 2) ? Qfrag : Wfrag;
    uint4 v;
    v.x = packh2(M[(k0+0)*256 + row], M[(k0+1)*256 + row]);
    v.y = packh2(M[(k0+2)*256 + row], M[(k0+3)*256 + row]);
    v.z = packh2(M[(k0+4)*256 + row], M[(k0+5)*256 + row]);
    v.w = packh2(M[(k0+6)*256 + row], M[(k0+7)*256 + row]);
    *(uint4*)&O[idx*4] = v;
}

// Pack D (row-major source) as A-fragments: A[n][d] = D[n*256+d].
__global__ void prep6(const float* __restrict__ D, u32* __restrict__ Dfrag) {
    int idx = blockIdx.x * 256 + threadIdx.x;   // 8192 threads
    int l   = idx & 63;
    int kk  = (idx >> 6) & 7;
    int tau = idx >> 9;
    int row = 16*tau + (l & 15);
    int k0  = 32*kk + 8*(l >> 4);
    float4 fa = *(const float4*)&D[row*256 + k0];
    float4 fb = *(const float4*)&D[row*256 + k0 + 4];
    uint4 v;
    v.x = packh2(fa.x, fa.y);
    v.y = packh2(fa.z, fa.w);
    v.z = packh2(fb.x, fb.y);
    v.w = packh2(fb.z, fb.w);
    *(uint4*)&Dfrag[idx*4] = v;
}

// ---------------------------------------------------------------------------
// zgemm2 (MFMA): Z[b][t][i] = sum_d W[i][d] y[b][d][t], written PACKED fp16:
//   Zh[(b*256+t)*128 + i/2] = (Z[..][i_even], Z[..][i_even+1])
// Block = (batch b, t-half). y staged to LDS as fp16 [t_local][d/2] u32 with
// XOR swizzle (dq ^ ((t&7)<<2)) so K-loop ds_read_b128 B-frags are
// conflict-free. A-frags (W) from prep4. Output via MFMA C-layout
// (col = lane&15 = t, rows = 16*tau + 4g + r) -> uint2 pair writes, exactly
// the index math scan9 uses to read Z.
// ---------------------------------------------------------------------------
__global__ __attribute__((amdgpu_flat_work_group_size(512, 512),
                          amdgpu_waves_per_eu(2)))
void zgemm2(const float* __restrict__ y, const u32* __restrict__ Wfrag,
            u32* __restrict__ Zh) {
    __shared__ u32 yl[16384];   // 64 KB: [t_local 0..127][dq 0..127] swizzled
    const int tid = threadIdx.x;
    const int l   = tid & 63;
    const int w   = tid >> 6;
    const int g   = l >> 4;
    const int c   = l & 15;
    const int b   = blockIdx.x;
    const int t0  = blockIdx.y * 128;

    // stage y -> fp16 LDS (transpose [d][t] -> [t][d/2] pairs)
    #pragma unroll
    for (int it = 0; it < 8; ++it) {
        int idx = it * 512 + tid;          // [0, 4096)
        int dp = idx >> 5;                 // d-pair 0..127
        int tq = idx & 31;                 // t-quad 0..31
        const float* yb = y + ((size_t)b*256 + 2*dp)*256 + t0 + 4*tq;
        float4 fa = *(const float4*)yb;
        float4 fb = *(const float4*)(yb + 256);
        const float* fav = (const float*)&fa;
        const float* fbv = (const float*)&fb;
        #pragma unroll
        for (int j = 0; j < 4; ++j) {
            int tl = 4*tq + j;
            yl[tl*128 + (dp ^ ((tl & 7) << 2))] = packh2(fav[j], fbv[j]);
        }
    }

    // A-fragments: W, tiles tau = 2w, 2w+1, all 8 kk
    f16x8 Wf0[8], Wf1[8];
    #pragma unroll
    for (int kk = 0; kk < 8; ++kk) {
        Wf0[kk] = __builtin_bit_cast(f16x8, *(const uint4*)&Wfrag[(((2*w+0)*8 + kk)*64 + l)*4]);
        Wf1[kk] = __builtin_bit_cast(f16x8, *(const uint4*)&Wfrag[(((2*w+1)*8 + kk)*64 + l)*4]);
    }
    __syncthreads();

    f32x4 acc0[8], acc1[8];
    #pragma unroll
    for (int tt = 0; tt < 8; ++tt) {
        acc0[tt] = (f32x4){0.f,0.f,0.f,0.f};
        acc1[tt] = (f32x4){0.f,0.f,0.f,0.f};
    }
    const int swz = (c & 7) << 2;
    #pragma unroll
    for (int tt = 0; tt < 8; ++tt) {
        const int tl = 16*tt + c;
        #pragma unroll
        for (int kk = 0; kk < 8; ++kk) {
            int idx = tl*128 + ((16*kk + 4*g) ^ swz);
            f16x8 bf = __builtin_bit_cast(f16x8, *(const uint4*)&yl[idx]);
            acc0[tt] = __builtin_amdgcn_mfma_f32_16x16x32_f16(Wf0[kk], bf, acc0[tt], 0, 0, 0);
            acc1[tt] = __builtin_amdgcn_mfma_f32_16x16x32_f16(Wf1[kk], bf, acc1[tt], 0, 0, 0);
        }
    }
    // epilogue: uint2 pairs at Zh[(b*256+t)*128 + 8*tau + 2g]
    #pragma unroll
    for (int tt = 0; tt < 8; ++tt) {
        const int t = t0 + 16*tt + c;
        uint2 p0, p1;
        p0.x = packh2(acc0[tt][0], acc0[tt][1]);
        p0.y = packh2(acc0[tt][2], acc0[tt][3]);
        p1.x = packh2(acc1[tt][0], acc1[tt][1]);
        p1.y = packh2(acc1[tt][2], acc1[tt][3]);
        u32* zp = &Zh[((size_t)(b*256 + t))*128 + 16*w + 2*g];
        *(uint2*)(zp)     = p0;
        *(uint2*)(zp + 8) = p1;
    }
}

// ---------------------------------------------------------------------------
// scan9: 4-round MFMA scan via Q-fusion.  Q = (S + c2 I) P folds the P-phase
// and iter-0 into one round:
//   round A: h1 = soft(Q h_prev + Z)   AND   const = Z + c2 * (P h_prev)
//   rounds B,C,D: h = soft(S h + const);  D stores H packed fp16.
// 16 blocks x 512 threads; wave w owns rows 32w..32w+31 (tiles 2w, 2w+1).
// ---------------------------------------------------------------------------
__global__ __attribute__((amdgpu_flat_work_group_size(512, 512),
                          amdgpu_waves_per_eu(2, 2)))
void scan9(const u32* __restrict__ Sfrag, const u32* __restrict__ Pfrag,
           const u32* __restrict__ Qfrag,
           const u32* __restrict__ Zh,
           const float* __restrict__ h0, const float* __restrict__ U,
           const float* __restrict__ lam1p, const float* __restrict__ lam2p,
           const float* __restrict__ alphap,
           u32* __restrict__ Hh) {
    __shared__ __align__(16) u32 hx[2 * 2048];   // 2 x 8 KB h B-fragment buffers

    const int tid = threadIdx.x;
    const int l   = tid & 63;
    const int w   = tid >> 6;          // wave 0..7
    const int lb  = l & 15;            // batch-in-group == MFMA col
    const int g   = l >> 4;            // 0..3
    const int b   = blockIdx.x * 16 + lb;

    const float inva = 1.0f / alphap[0];
    const float bt   = lam1p[0] * inva;
    const float c2   = lam2p[0] * inva;

    // per-lane rows: 32w + 16T + 4g + r
    const int rb = 32*w + 4*g;
    const float u00 = U[rb+0]*bt,  u01 = U[rb+1]*bt,  u02 = U[rb+2]*bt,  u03 = U[rb+3]*bt;
    const float u10 = U[rb+16]*bt, u11 = U[rb+17]*bt, u12 = U[rb+18]*bt, u13 = U[rb+19]*bt;

    // A-fragments -> AGPR-backed registers (coalesced uint4 loads)
    f16x8 Sf0[8], Sf1[8], Pf0[8], Pf1[8], Qf0[8], Qf1[8];
    #pragma unroll
    for (int kk = 0; kk < 8; ++kk) {
        Sf0[kk] = __builtin_bit_cast(f16x8, *(const uint4*)&Sfrag[(((2*w+0)*8 + kk)*64 + l)*4]);
        Sf1[kk] = __builtin_bit_cast(f16x8, *(const uint4*)&Sfrag[(((2*w+1)*8 + kk)*64 + l)*4]);
        Pf0[kk] = __builtin_bit_cast(f16x8, *(const uint4*)&Pfrag[(((2*w+0)*8 + kk)*64 + l)*4]);
        Pf1[kk] = __builtin_bit_cast(f16x8, *(const uint4*)&Pfrag[(((2*w+1)*8 + kk)*64 + l)*4]);
        Qf0[kk] = __builtin_bit_cast(f16x8, *(const uint4*)&Qfrag[(((2*w+0)*8 + kk)*64 + l)*4]);
        Qf1[kk] = __builtin_bit_cast(f16x8, *(const uint4*)&Qfrag[(((2*w+1)*8 + kk)*64 + l)*4]);
    }

    // init h_prev B-fragments into buf0 (h0 is batch-independent)
    {
        int k0 = 32*(tid >> 6) + 8*((tid & 63) >> 4);
        uint4 hv;
        hv.x = packh2(h0[k0+0], h0[k0+1]);
        hv.y = packh2(h0[k0+2], h0[k0+3]);
        hv.z = packh2(h0[k0+4], h0[k0+5]);
        hv.w = packh2(h0[k0+6], h0[k0+7]);
        *(uint4*)&hx[tid*4] = hv;
    }
    __syncthreads();

    // Z: uint2 at Zb[t*128 + 8T] covers i = 32w + 16T + 4g + {0..3}
    const u32* Zb = Zh + (size_t)b*32768 + 16*w + 2*g;
    u32* Hbh = Hh + (size_t)b*32768 + 16*w + 2*g;   // same index math as Zb

    // write slot (u32 index inside a buffer) for this lane's tile-T=0 pair;
    // tile-T=1 is +128.  (kk = w slice; lane'' = (2T + (g>>1))*16 + lb)
    const int wb0 = w*256 + (((g>>1))*16 + lb)*4 + (g&1)*2;

    uint2 z0 = *(const uint2*)&Zb[0];
    uint2 z1 = *(const uint2*)&Zb[8];

    #pragma unroll 1
    for (int t = 0; t < TLEN; ++t) {
        // ---- Round A: q = Q h_prev (+Z init), a = P h_prev ----
        f16x8 hb[8];
        #pragma unroll
        for (int kk = 0; kk < 8; ++kk)
            hb[kk] = __builtin_bit_cast(f16x8, *(const uint4*)&hx[0 + (kk*64 + l)*4]);
        f32x4 q0 = {h2lo(z0.x), h2hi(z0.x), h2lo(z0.y), h2hi(z0.y)};
        f32x4 q1 = {h2lo(z1.x), h2hi(z1.x), h2lo(z1.y), h2hi(z1.y)};
        f32x4 a0 = {0.f,0.f,0.f,0.f}, a1 = {0.f,0.f,0.f,0.f};
        #pragma unroll
        for (int kk = 0; kk < 8; ++kk) {
            q0 = __builtin_amdgcn_mfma_f32_16x16x32_f16(Qf0[kk], hb[kk], q0, 0, 0, 0);
            q1 = __builtin_amdgcn_mfma_f32_16x16x32_f16(Qf1[kk], hb[kk], q1, 0, 0, 0);
            a0 = __builtin_amdgcn_mfma_f32_16x16x32_f16(Pf0[kk], hb[kk], a0, 0, 0, 0);
            a1 = __builtin_amdgcn_mfma_f32_16x16x32_f16(Pf1[kk], hb[kk], a1, 0, 0, 0);
        }
        // h1 = soft(q)
        {
            const float h00 = copysignf(fmaxf(fabsf(q0[0]) - u00, 0.f), q0[0]);
            const float h01 = copysignf(fmaxf(fabsf(q0[1]) - u01, 0.f), q0[1]);
            const float h02 = copysignf(fmaxf(fabsf(q0[2]) - u02, 0.f), q0[2]);
            const float h03 = copysignf(fmaxf(fabsf(q0[3]) - u03, 0.f), q0[3]);
            const float h10 = copysignf(fmaxf(fabsf(q1[0]) - u10, 0.f), q1[0]);
            const float h11 = copysignf(fmaxf(fabsf(q1[1]) - u11, 0.f), q1[1]);
            const float h12 = copysignf(fmaxf(fabsf(q1[2]) - u12, 0.f), q1[2]);
            const float h13 = copysignf(fmaxf(fabsf(q1[3]) - u13, 0.f), q1[3]);
            *(uint2*)&hx[2048 + wb0]       = make_uint2(packh2(h00,h01), packh2(h02,h03));
            *(uint2*)&hx[2048 + wb0 + 128] = make_uint2(packh2(h10,h11), packh2(h12,h13));
        }
        __syncthreads();

        // Z prefetch for t+1 (used ~4 rounds from now - fully hidden)
        const int tn = (t < TLEN-1) ? t + 1 : t;
        uint2 zn0 = *(const uint2*)&Zb[(size_t)tn*128];
        uint2 zn1 = *(const uint2*)&Zb[(size_t)tn*128 + 8];

        // const = Z + c2 * (P h_prev)  (off critical path; hides under B's reads)
        const float c00 = h2lo(z0.x) + c2*a0[0];
        const float c01 = h2hi(z0.x) + c2*a0[1];
        const float c02 = h2lo(z0.y) + c2*a0[2];
        const float c03 = h2hi(z0.y) + c2*a0[3];
        const float c10 = h2lo(z1.x) + c2*a1[0];
        const float c11 = h2hi(z1.x) + c2*a1[1];
        const float c12 = h2lo(z1.y) + c2*a1[2];
        const float c13 = h2hi(z1.y) + c2*a1[3];

        // ---- Rounds B,C,D: h = soft(S h + const) ----
        #pragma unroll
        for (int it = 0; it < 3; ++it) {
            const int rd = (it & 1) ? 0 : 2048;
            const int wr = (it & 1) ? 2048 : 0;
            #pragma unroll
            for (int kk = 0; kk < 8; ++kk)
                hb[kk] = __builtin_bit_cast(f16x8, *(const uint4*)&hx[rd + (kk*64 + l)*4]);
            f32x4 s0 = {c00,c01,c02,c03};
            f32x4 s1 = {c10,c11,c12,c13};
            #pragma unroll
            for (int kk = 0; kk < 8; ++kk) {
                s0 = __builtin_amdgcn_mfma_f32_16x16x32_f16(Sf0[kk], hb[kk], s0, 0, 0, 0);
                s1 = __builtin_amdgcn_mfma_f32_16x16x32_f16(Sf1[kk], hb[kk], s1, 0, 0, 0);
            }
            const float h00 = copysignf(fmaxf(fabsf(s0[0]) - u00, 0.f), s0[0]);
            const float h01 = copysignf(fmaxf(fabsf(s0[1]) - u01, 0.f), s0[1]);
            const float h02 = copysignf(fmaxf(fabsf(s0[2]) - u02, 0.f), s0[2]);
            const float h03 = copysignf(fmaxf(fabsf(s0[3]) - u03, 0.f), s0[3]);
            const float h10 = copysignf(fmaxf(fabsf(s1[0]) - u10, 0.f), s1[0]);
            const float h11 = copysignf(fmaxf(fabsf(s1[1]) - u11, 0.f), s1[1]);
            const float h12 = copysignf(fmaxf(fabsf(s1[2]) - u12, 0.f), s1[2]);
            const float h13 = copysignf(fmaxf(fabsf(s1[3]) - u13, 0.f), s1[3]);
            *(uint2*)&hx[wr + wb0]       = make_uint2(packh2(h00,h01), packh2(h02,h03));
            *(uint2*)&hx[wr + wb0 + 128] = make_uint2(packh2(h10,h11), packh2(h12,h13));
            __syncthreads();
            if (it == 2) {   // fire-and-forget fp16 H store; drains next round A
                *(uint2*)&Hbh[(size_t)t*128]     = make_uint2(packh2(h00,h01), packh2(h02,h03));
                *(uint2*)&Hbh[(size_t)t*128 + 8] = make_uint2(packh2(h10,h11), packh2(h12,h13));
            }
        }
        z0 = zn0; z1 = zn1;
    }
}

// ---------------------------------------------------------------------------
// ogemm2 (MFMA): out[b][n][t] = sum_d D[n][d] * H[b][t][d], H packed fp16.
// Block = (batch b, t-half). H staged LDS via swizzled uint4 memcpy; A-frags
// (D) from prep6. Same K-loop structure as zgemm2.
// ---------------------------------------------------------------------------
__global__ __attribute__((amdgpu_flat_work_group_size(512, 512),
                          amdgpu_waves_per_eu(2)))
void ogemm2(const u32* __restrict__ Dfrag, const u32* __restrict__ Hh,
            float* __restrict__ out) {
    __shared__ u32 hl[16384];   // 64 KB: [t_local][dq] swizzled
    const int tid = threadIdx.x;
    const int l   = tid & 63;
    const int w   = tid >> 6;
    const int g   = l >> 4;
    const int c   = l & 15;
    const int b   = blockIdx.x;
    const int t0  = blockIdx.y * 128;

    // stage H (already fp16-packed): swizzled uint4 copy
    const uint4* Hg = (const uint4*)(Hh + (size_t)b*32768 + (size_t)t0*128);
    #pragma unroll
    for (int it = 0; it < 8; ++it) {
        int j4 = it * 512 + tid;           // uint4 index [0,4096)
        int tl = j4 >> 5, m = j4 & 31;
        ((uint4*)hl)[tl*32 + (m ^ (tl & 7))] = Hg[j4];
    }

    // A-fragments: D, tiles tau = 2w, 2w+1
    f16x8 Df0[8], Df1[8];
    #pragma unroll
    for (int kk = 0; kk < 8; ++kk) {
        Df0[kk] = __builtin_bit_cast(f16x8, *(const uint4*)&Dfrag[(((2*w+0)*8 + kk)*64 + l)*4]);
        Df1[kk] = __builtin_bit_cast(f16x8, *(const uint4*)&Dfrag[(((2*w+1)*8 + kk)*64 + l)*4]);
    }
    __syncthreads();

    f32x4 acc0[8], acc1[8];
    #pragma unroll
    for (int tt = 0; tt < 8; ++tt) {
        acc0[tt] = (f32x4){0.f,0.f,0.f,0.f};
        acc1[tt] = (f32x4){0.f,0.f,0.f,0.f};
    }
    const int swz = (c & 7) << 2;
    #pragma unroll
    for (int tt = 0; tt < 8; ++tt) {
        const int tl = 16*tt + c;
        #pragma unroll
        for (int kk = 0; kk < 8; ++kk) {
            int idx = tl*128 + ((16*kk + 4*g) ^ swz);
            f16x8 bf = __builtin_bit_cast(f16x8, *(const uint4*)&hl[idx]);
            acc0[tt] = __builtin_amdgcn_mfma_f32_16x16x32_f16(Df0[kk], bf, acc0[tt], 0, 0, 0);
            acc1[tt] = __builtin_amdgcn_mfma_f32_16x16x32_f16(Df1[kk], bf, acc1[tt], 0, 0, 0);
        }
    }
    // epilogue: out[b][n][t], n = 16*tau + 4g + r, t = t0 + 16tt + c
    #pragma unroll
    for (int tt = 0; tt < 8; ++tt) {
        const int t = t0 + 16*tt + c;
        const int n0 = 16*(2*w+0) + 4*g;
        const int n1 = 16*(2*w+1) + 4*g;
        #pragma unroll
        for (int r = 0; r < 4; ++r) {
            out[((size_t)(b*256) + n0 + r)*256 + t] = acc0[tt][r];
            out[((size_t)(b*256) + n1 + r)*256 + t] = acc1[tt][r];
        }
    }
}

// ---------------------------------------------------------------------------
extern "C" void kernel_launch(void* const* d_in, const int* in_sizes, int n_in,
                              void* d_out, int out_size, void* d_ws, size_t ws_size,
                              hipStream_t stream) {
    const float* y     = (const float*)d_in[0];
    const float* A     = (const float*)d_in[1];
    const float* D     = (const float*)d_in[2];
    const float* F     = (const float*)d_in[3];
    const float* lam1  = (const float*)d_in[4];
    const float* lam2  = (const float*)d_in[5];
    const float* alpha = (const float*)d_in[6];
    const float* h0    = (const float*)d_in[7];
    const float* U     = (const float*)d_in[8];
    float* out = (float*)d_out;
    float* ws  = (float*)d_ws;

    // ws layout (fp32-element offsets)
    const size_t oZ  = 0;           // Zh u32 (8.39M region 16.7M)
    const size_t oH  = 16777216;    // Hh u32 packed fp16 (8.39M of 16.7M region)
    const size_t oWt = 33554432;
    const size_t oSt = 33619968;
    const size_t oPt = 33685504;
    const size_t oFD = 33751040;    // FD during prep1/2; Qt afterwards (65536)
    const size_t oG  = 33816576;    // G during prep1/2; Qfrag afterwards (32768 u32)
    const size_t oGD = 33882112;    // GD during prep2/3; Wfrag+Dfrag afterwards
    const size_t oAD = 33947648;
    const size_t oSh = 33964032;   // Sfrag u32 (32768)
    const size_t oPh = 33996800;   // Pfrag u32 (32768)

    u32*   Zh = (u32*)(ws + oZ);
    u32*   Hh = (u32*)(ws + oH);
    float* Wt = ws + oWt; float* St = ws + oSt; float* Pt = ws + oPt;
    float* FD = ws + oFD; float* G  = ws + oG;  float* GD = ws + oGD;
    float* AD = ws + oAD;
    float* Qt = ws + oFD;            // reuse FD region (dead after prep2)
    u32* Sfrag = (u32*)(ws + oSh);
    u32* Pfrag = (u32*)(ws + oPh);
    u32* Qfrag = (u32*)(ws + oG);    // reuse G region (dead after prep2)
    u32* Wfrag = (u32*)(ws + oGD);            // reuse GD region (dead after prep3)
    u32* Dfrag = (u32*)(ws + oGD + 32768);    // second half of GD region

    prep1<<<576, 256, 0, stream>>>(A, D, F, lam2, FD, G, AD);
    prep2<<<768, 256, 0, stream>>>(A, D, alpha, FD, G, AD, Pt, GD, Wt);
    prep3<<<256, 256, 0, stream>>>(D, GD, alpha, St);
    prep5<<<256, 256, 0, stream>>>(St, Pt, lam2, alpha, Qt);
    prep4<<<128, 256, 0, stream>>>(St, Pt, Qt, Wt, Sfrag, Pfrag, Qfrag, Wfrag);
    prep6<<<32, 256, 0, stream>>>(D, Dfrag);
    {
        dim3 gz(256, 2);
        zgemm2<<<gz, 512, 0, stream>>>(y, Wfrag, Zh);
    }
    scan9<<<16, 512, 0, stream>>>(Sfrag, Pfrag, Qfrag, Zh, h0, U, lam1, lam2, alpha, Hh);
    {
        dim3 go(256, 2);
        ogemm2<<<go, 512, 0, stream>>>(Dfrag, Hh, out);
    }
}